// Round 21
// baseline (346.686 us; speedup 1.0000x reference)
//
#include <hip/hip_runtime.h>
#include <hip/hip_bf16.h>
#include <hip/hip_fp8.h>
#include <math.h>

typedef __hip_bfloat16 bf16;
typedef unsigned char uchar;
typedef unsigned long long u64;
typedef __attribute__((ext_vector_type(8))) short short8;
typedef __attribute__((ext_vector_type(4))) float f32x4;
typedef __attribute__((ext_vector_type(2))) float f32x2;
typedef __attribute__((ext_vector_type(4))) unsigned uint4v;
typedef __attribute__((ext_vector_type(2))) u64 u64x2;

__device__ __forceinline__ float b2f(short s) {
  unsigned u = ((unsigned)(unsigned short)s) << 16;
  return __builtin_bit_cast(float, u);
}
__device__ __forceinline__ short f2b(float f) {
  bf16 h = __float2bfloat16(f);
  return *reinterpret_cast<short*>(&h);
}

#if defined(__has_builtin)
#if __has_builtin(__builtin_amdgcn_cvt_pk_fp8_f32) && \
    __has_builtin(__builtin_amdgcn_cvt_pk_f32_fp8)
#define HWFP8 1
#endif
#endif

#ifdef HWFP8
__device__ __forceinline__ unsigned pk4q(float a, float b, float c, float d) {
  int r = __builtin_amdgcn_cvt_pk_fp8_f32(a, b, 0, false);
  r = __builtin_amdgcn_cvt_pk_fp8_f32(c, d, r, true);
  return (unsigned)r;
}
__device__ __forceinline__ void upk4(unsigned w, float* o) {
  f32x2 lo = __builtin_amdgcn_cvt_pk_f32_fp8((int)w, false);
  f32x2 hi = __builtin_amdgcn_cvt_pk_f32_fp8((int)w, true);
  o[0] = lo[0];
  o[1] = lo[1];
  o[2] = hi[0];
  o[3] = hi[1];
}
#else
__device__ __forceinline__ uchar f2q_(float f) {
  __hip_fp8_e4m3 t(f);
  return (uchar)t.__x;
}
__device__ __forceinline__ float q2f_(uchar c) {
  __hip_fp8_e4m3 t;
  t.__x = (__hip_fp8_storage_t)c;
  return (float)t;
}
__device__ __forceinline__ unsigned pk4q(float a, float b, float c, float d) {
  return (unsigned)f2q_(a) | ((unsigned)f2q_(b) << 8) |
         ((unsigned)f2q_(c) << 16) | ((unsigned)f2q_(d) << 24);
}
__device__ __forceinline__ void upk4(unsigned w, float* o) {
  o[0] = q2f_((uchar)(w & 255));
  o[1] = q2f_((uchar)((w >> 8) & 255));
  o[2] = q2f_((uchar)((w >> 16) & 255));
  o[3] = q2f_((uchar)((w >> 24) & 255));
}
#endif

// XCD-chunked bijective block swizzle (grid size must be %8==0)
__device__ __forceinline__ void xcd_swz(unsigned& bx, unsigned& by,
                                        unsigned& bz) {
  unsigned nbx = gridDim.x, nby = gridDim.y, nbz = gridDim.z;
  unsigned lin = blockIdx.x + nbx * (blockIdx.y + nby * blockIdx.z);
  unsigned q = (nbx * nby * nbz) >> 3;
  unsigned nl = (lin & 7) * q + (lin >> 3);
  bx = nl % nbx;
  unsigned rest = nl / nbx;
  by = rest % nby;
  bz = rest / nby;
}

// ---------------- smallws helper: DCT matrix only ----------------
__global__ void k_build_dct(float* __restrict__ D) {
  int k = blockIdx.x, i = threadIdx.x;
  double v = cos(3.14159265358979323846 * (2.0 * i + 1.0) * (double)k / 512.0) *
             0.08838834764831845;
  if (k == 0) v *= 0.7071067811865476;
  D[k * 256 + i] = (float)v;
}

// ---- merged init (bigws): blocks 0..255 build DCT; 256..264 pack fp8 weights --
__global__ void k_init(float* __restrict__ D, const float* __restrict__ w1,
                       const float* __restrict__ wc, uchar* __restrict__ wp) {
  int blk = blockIdx.x;
  if (blk < 256) {
    int k = blk, i = threadIdx.x;
    double v = cos(3.14159265358979323846 * (2.0 * i + 1.0) * (double)k /
                   512.0) *
               0.08838834764831845;
    if (k == 0) v *= 0.7071067811865476;
    D[k * 256 + i] = (float)v;
  } else {
    int set = blk - 256;
    const float* w;
    int C, cbase;
    if (set < 2) {
      w = w1;
      C = 64;
      cbase = set * 32;
    } else {
      w = wc + (set - 2) * 9216;
      C = 32;
      cbase = 0;
    }
    for (int d4 = threadIdx.x; d4 < 2304; d4 += 256) {
      float f[4];
#pragma unroll
      for (int j = 0; j < 4; ++j) {
        int d = d4 * 4 + j;
        int k = d & 7, l = (d >> 3) & 63, ct = (d >> 9) & 1, tap = d >> 10;
        int co = ct * 16 + (l & 15), cin = (l >> 4) * 8 + k;
        f[j] = w[(co * C + cbase + cin) * 9 + tap];
      }
      *(unsigned*)(wp + set * 9216 + d4 * 4) = pk4q(f[0], f[1], f[2], f[3]);
    }
  }
}

// ---- stage1: M1 = D @ X, fp32, k-ascending single accumulator (BLAS order) ----
__global__ __launch_bounds__(256) void k_dct1(const float* __restrict__ D,
                                              const float* __restrict__ x,
                                              float* __restrict__ M1) {
  __shared__ __align__(16) float As[32][84];
  __shared__ __align__(16) float Bs[32][80];
  int tid = threadIdx.x;
  int tx = tid & 15, ty = tid >> 4;
  int k0 = blockIdx.x * 64, i0 = blockIdx.y * 64;
  size_t base = (size_t)blockIdx.z * 65536;
  float acc[4][4];
#pragma unroll
  for (int a = 0; a < 4; ++a)
#pragma unroll
    for (int c = 0; c < 4; ++c) acc[a][c] = 0.f;
  for (int kk = 0; kk < 256; kk += 32) {
    __syncthreads();
#pragma unroll
    for (int s = 0; s < 2; ++s) {
      int idx = s * 256 + tid;
      int i = idx >> 3, k4 = (idx & 7) * 4;
      f32x4 d4 = *(const f32x4*)&D[(i0 + i) * 256 + kk + k4];
#pragma unroll
      for (int q = 0; q < 4; ++q) As[k4 + q][i] = d4[q];
      int j = idx >> 4, c4 = (idx & 15) * 4;
      *(f32x4*)&Bs[j][c4] =
          *(const f32x4*)&x[base + (size_t)(kk + j) * 256 + k0 + c4];
    }
    __syncthreads();
#pragma unroll
    for (int k = 0; k < 32; ++k) {
      f32x4 a4 = *(const f32x4*)&As[k][ty * 4];
      f32x4 b4 = *(const f32x4*)&Bs[k][tx * 4];
#pragma unroll
      for (int ii = 0; ii < 4; ++ii)
#pragma unroll
        for (int jj = 0; jj < 4; ++jj)
          acc[ii][jj] = fmaf(a4[ii], b4[jj], acc[ii][jj]);
    }
  }
#pragma unroll
  for (int ii = 0; ii < 4; ++ii) {
    f32x4 o = {acc[ii][0], acc[ii][1], acc[ii][2], acc[ii][3]};
    *(f32x4*)&M1[base + (size_t)(i0 + ty * 4 + ii) * 256 + k0 + tx * 4] = o;
  }
}

// ---- stage2: xf = lognorm(M1 @ D^T) ----
__global__ __launch_bounds__(256) void k_dct2(const float* __restrict__ M1,
                                              const float* __restrict__ D,
                                              const float* __restrict__ dmean,
                                              const float* __restrict__ dstd,
                                              float* __restrict__ xf) {
  __shared__ __align__(16) float As[32][84];
  __shared__ __align__(16) float Bs[32][84];
  int tid = threadIdx.x;
  int tx = tid & 15, ty = tid >> 4;
  int l0 = blockIdx.x * 64, i0 = blockIdx.y * 64;
  int bc = blockIdx.z;
  size_t base = (size_t)bc * 65536;
  int ch = bc % 3;
  float acc[4][4];
#pragma unroll
  for (int a = 0; a < 4; ++a)
#pragma unroll
    for (int c = 0; c < 4; ++c) acc[a][c] = 0.f;
  for (int kk = 0; kk < 256; kk += 32) {
    __syncthreads();
#pragma unroll
    for (int s = 0; s < 2; ++s) {
      int idx = s * 256 + tid;
      int i = idx >> 3, k4 = (idx & 7) * 4;
      f32x4 a4 = *(const f32x4*)&M1[base + (size_t)(i0 + i) * 256 + kk + k4];
      f32x4 b4 = *(const f32x4*)&D[(l0 + i) * 256 + kk + k4];
#pragma unroll
      for (int q = 0; q < 4; ++q) {
        As[k4 + q][i] = a4[q];
        Bs[k4 + q][i] = b4[q];
      }
    }
    __syncthreads();
#pragma unroll
    for (int k = 0; k < 32; ++k) {
      f32x4 a4 = *(const f32x4*)&As[k][ty * 4];
      f32x4 b4 = *(const f32x4*)&Bs[k][tx * 4];
#pragma unroll
      for (int ii = 0; ii < 4; ++ii)
#pragma unroll
        for (int jj = 0; jj < 4; ++jj)
          acc[ii][jj] = fmaf(a4[ii], b4[jj], acc[ii][jj]);
    }
  }
#pragma unroll
  for (int ii = 0; ii < 4; ++ii) {
    int ig = i0 + ty * 4 + ii;
    int ll = l0 + tx * 4;
    int mi = (ch * 256 + ig) * 256 + ll;
    f32x4 dm = *(const f32x4*)&dmean[mi];
    f32x4 ds = *(const f32x4*)&dstd[mi];
    f32x4 o;
#pragma unroll
    for (int jj = 0; jj < 4; ++jj)
      o[jj] = (logf(fabsf(acc[ii][jj]) + 1e-13f) - dm[jj]) / ds[jj];
    *(f32x4*)&xf[base + (size_t)ig * 256 + ll] = o;
  }
}

// ------- front conv (bigws): 3->32 both branches + bn0 + relu
//   -> NHWC32 fp8 planes (LDS-bounced) + fp32 NCHW feat (NT, registers)
__global__ __launch_bounds__(256) void k_front_n(
    const float* __restrict__ x, const float* __restrict__ xf,
    const float* __restrict__ w_spa, const float* __restrict__ b_spa,
    const float* __restrict__ w_fre, const float* __restrict__ b_fre,
    const float* __restrict__ g, const float* __restrict__ bb,
    const float* __restrict__ m, const float* __restrict__ vv,
    uchar* __restrict__ featN0, uchar* __restrict__ featN1,
    float* __restrict__ feat) {
  __shared__ __align__(16) float xin[3 * 4 * 264];
  __shared__ __align__(16) short fstage[2 * 256 * 32];
  __shared__ float wl[864];
  __shared__ float sc[32], sh[32];
  unsigned sbx, sby, sbz;
  xcd_swz(sbx, sby, sbz);
  int z = sbz;
  const float* in = z ? xf : x;
  const float* w = z ? w_fre : w_spa;
  const float* bias = z ? b_fre : b_spa;
  int tid = threadIdx.x;
  int b = sby;
  int y0 = sbx * 2;
  for (int i = tid; i < 864; i += 256) wl[i] = w[i];
  if (tid < 32) {
    int cgl = z * 32 + tid;
    float s = g[cgl] * rsqrtf(vv[cgl] + 1e-5f);
    sc[tid] = s;
    sh[tid] = (bias[tid] - m[cgl]) * s + bb[cgl];
  }
  const float* inb = in + (size_t)b * 3 * 65536;
  for (int i = tid; i < 792; i += 256) {
    int ci = i / 264, rem = i - ci * 264;
    int r = rem / 66, c = rem - r * 66;
    int gy = y0 - 1 + r;
    f32x4 v = {0.f, 0.f, 0.f, 0.f};
    if ((unsigned)gy < 256u && c >= 1 && c <= 64)
      v = *(const f32x4*)&inb[((size_t)ci << 16) + (gy << 8) + (c * 4 - 4)];
    *(f32x4*)&xin[(ci * 4 + r) * 264 + c * 4] = v;
  }
  __syncthreads();
  int xq = tid & 63, cg = tid >> 6;
  int x0 = xq * 4;
  float acc[2][4][8];
#pragma unroll
  for (int r = 0; r < 2; ++r)
#pragma unroll
    for (int p = 0; p < 4; ++p)
#pragma unroll
      for (int co = 0; co < 8; ++co) acc[r][p][co] = 0.f;
  for (int ci = 0; ci < 3; ++ci) {
    float v[4][6];
#pragma unroll
    for (int r = 0; r < 4; ++r) {
      const float* row = &xin[(ci * 4 + r) * 264];
      f32x4 qA = *(const f32x4*)&row[x0];
      f32x4 qB = *(const f32x4*)&row[x0 + 4];
      f32x4 qC = *(const f32x4*)&row[x0 + 8];
      v[r][0] = qA[3];
      v[r][1] = qB[0];
      v[r][2] = qB[1];
      v[r][3] = qB[2];
      v[r][4] = qB[3];
      v[r][5] = qC[0];
    }
#pragma unroll
    for (int co = 0; co < 8; ++co) {
      int cob = cg * 8 + co;
      float w9[9];
#pragma unroll
      for (int t = 0; t < 9; ++t) w9[t] = wl[cob * 27 + ci * 9 + t];
#pragma unroll
      for (int ky = 0; ky < 3; ++ky)
#pragma unroll
        for (int kx = 0; kx < 3; ++kx) {
          float wv = w9[ky * 3 + kx];
#pragma unroll
          for (int r = 0; r < 2; ++r)
#pragma unroll
            for (int p = 0; p < 4; ++p)
              acc[r][p][co] = fmaf(v[r + ky][p + kx], wv, acc[r][p][co]);
        }
    }
  }
#pragma unroll
  for (int r = 0; r < 2; ++r) {
#pragma unroll
    for (int p = 0; p < 4; ++p) {
      short8 s8;
#pragma unroll
      for (int co = 0; co < 8; ++co) {
        float val = acc[r][p][co] * sc[cg * 8 + co] + sh[cg * 8 + co];
        val = val > 0.f ? val : 0.f;
        acc[r][p][co] = val;
        s8[co] = f2b(val);
      }
      int scg = cg ^ p ^ (xq & 3);
      *(short8*)&fstage[((r * 256 + x0 + p) << 5) + (scg << 3)] = s8;
    }
#pragma unroll
    for (int co = 0; co < 8; ++co) {
      f32x4 o = {acc[r][0][co], acc[r][1][co], acc[r][2][co], acc[r][3][co]};
      f32x4* dst = (f32x4*)&feat[(((size_t)(b * 64 + z * 32 + cg * 8 + co))
                                  << 16) +
                                 ((y0 + r) << 8) + x0];
      __builtin_nontemporal_store(o, dst);
    }
  }
  __syncthreads();
  uchar* fp = z ? featN1 : featN0;
  size_t rowbase = ((size_t)(b * 256 + y0) * 256) * 32;
#pragma unroll
  for (int k = 0; k < 8; ++k) {
    int c = k * 256 + tid;
    int p2 = (c >> 2) & 255;
    int r = c >> 10;
    int cgc = c & 3;
    int scg = cgc ^ (p2 & 3) ^ ((p2 >> 2) & 3);
    short8 v = *(short8*)&fstage[((r * 256 + p2) << 5) + (scg << 3)];
    uint2 pk2;
    pk2.x = pk4q(b2f(v[0]), b2f(v[1]), b2f(v[2]), b2f(v[3]));
    pk2.y = pk4q(b2f(v[4]), b2f(v[5]), b2f(v[6]), b2f(v[7]));
    *(uint2*)(fp + rowbase + (size_t)c * 8) = pk2;
  }
}

// ===== fp8-native MFMA conv3x3: NP fp8 NHWC32 planes in -> fp8 NHWC32 out =====
template <int TX, int NP, int YB, bool POOL>
__global__ __launch_bounds__(256) void k_conv8(
    const uchar* __restrict__ in0, const uchar* __restrict__ in1,
    const uchar* __restrict__ wp, const float* __restrict__ bias,
    const float* __restrict__ g, const float* __restrict__ bb,
    const float* __restrict__ m, const float* __restrict__ vv,
    uchar* __restrict__ out, int H) {
  constexpr int XT = TX + 2;
  constexpr int NR = (TX == 64) ? YB : 2;
  constexpr int YR = ((TX == 64) ? YB : 4) + 2;
  __shared__ u64 tile64[YR * XT * 4];  // 32 B/pos, 8-B chunks
  __shared__ float sc[32], sh[32];
  unsigned sbx, sby, sbz;
  xcd_swz(sbx, sby, sbz);
  int tid = threadIdx.x;
  int lane = tid & 63, wid = tid >> 6;
  int W = H;
  int b = sbz, y0 = sby * ((TX == 64) ? YB : 4), x0 = sbx * TX;
  if (tid < 32) {
    float s = g[tid] * rsqrtf(vv[tid] + 1e-5f);
    sc[tid] = s;
    sh[tid] = (bias[tid] - m[tid]) * s + bb[tid];
  }
  int px = lane & 15, g4 = lane >> 4;
  int RB = (TX == 64) ? 0 : (wid >> 1) * 2;
  int wx = (TX == 64) ? wid : (wid & 1);
  f32x4 acc[NR][2];
#pragma unroll
  for (int r = 0; r < NR; ++r)
#pragma unroll
    for (int ct = 0; ct < 2; ++ct) acc[r][ct] = {0.f, 0.f, 0.f, 0.f};

  for (int cb = 0; cb < NP; ++cb) {
    if (cb) __syncthreads();
    const uchar* in = cb ? in1 : in0;
    for (int i = tid; i < YR * XT * 2; i += 256) {
      int ir = i / (XT * 2), rem = i - ir * (XT * 2);
      int xl = rem >> 1, c2 = rem & 1;
      int gy = y0 - 1 + ir, gx = x0 - 1 + xl;
      u64x2 raw = {0, 0};
      if ((unsigned)gy < (unsigned)H && (unsigned)gx < (unsigned)W)
        raw = *(const u64x2*)(in + ((size_t)(b * H + gy) * W + gx) * 32 +
                              c2 * 16);
      int sw = (xl & 3) ^ ((xl >> 2) & 3);
      int base4 = (ir * XT + xl) * 4;
      tile64[base4 + ((c2 * 2) ^ sw)] = raw[0];
      tile64[base4 + ((c2 * 2 + 1) ^ sw)] = raw[1];
    }
    __syncthreads();
    u64 wf[9][2];
#pragma unroll
    for (int tap = 0; tap < 9; ++tap)
#pragma unroll
      for (int ct = 0; ct < 2; ++ct)
        wf[tap][ct] = *(const u64*)(wp + cb * 9216 +
                                    ((((tap * 2 + ct) << 6) + lane) << 3));
#pragma unroll
    for (int dx = 0; dx < 3; ++dx) {
      int xl = wx * 16 + px + dx;
      int cs = g4 ^ (xl & 3) ^ ((xl >> 2) & 3);
      u64 fr[NR + 2];
#pragma unroll
      for (int ir = 0; ir < NR + 2; ++ir)
        fr[ir] = tile64[((RB + ir) * XT + xl) * 4 + cs];
#pragma unroll
      for (int dy = 0; dy < 3; ++dy)
#pragma unroll
        for (int r = 0; r < NR; ++r)
#pragma unroll
          for (int ct = 0; ct < 2; ++ct)
            acc[r][ct] = __builtin_amdgcn_mfma_f32_16x16x32_fp8_fp8(
                (long)wf[dy * 3 + dx][ct], (long)fr[r + dy], acc[r][ct], 0, 0,
                0);
    }
  }
  int xg = x0 + wx * 16 + px;
  if constexpr (POOL) {
    int H2 = H >> 1;
#pragma unroll
    for (int pr = 0; pr < NR / 2; ++pr) {
#pragma unroll
      for (int ct = 0; ct < 2; ++ct) {
        float o4[4];
#pragma unroll
        for (int q = 0; q < 4; ++q) {
          int co = ct * 16 + g4 * 4 + q;
          float v0 = acc[2 * pr][ct][q] * sc[co] + sh[co];
          float v1 = acc[2 * pr + 1][ct][q] * sc[co] + sh[co];
          v0 = v0 > 0.f ? v0 : 0.f;
          v1 = v1 > 0.f ? v1 : 0.f;
          float s2 = v0 + v1;
          o4[q] = 0.25f * (s2 + __shfl_xor(s2, 1, 64));
        }
        if (!(px & 1)) {
          int row = (y0 + RB + 2 * pr) >> 1;
          unsigned pk = pk4q(o4[0], o4[1], o4[2], o4[3]);
          size_t ob = ((size_t)(b * H2 + row) * H2 + (xg >> 1)) * 32 +
                      ct * 16 + g4 * 4;
          *(unsigned*)(out + ob) = pk;
        }
      }
    }
  } else {
#pragma unroll
    for (int r = 0; r < NR; ++r) {
      int y = y0 + RB + r;
#pragma unroll
      for (int ct = 0; ct < 2; ++ct) {
        float o4[4];
#pragma unroll
        for (int q = 0; q < 4; ++q) {
          int co = ct * 16 + g4 * 4 + q;
          float val = acc[r][ct][q] * sc[co] + sh[co];
          o4[q] = val > 0.f ? val : 0.f;
        }
        unsigned pk = pk4q(o4[0], o4[1], o4[2], o4[3]);
        size_t ob = ((size_t)(b * H + y) * W + xg) * 32 + ct * 16 + g4 * 4;
        *(unsigned*)(out + ob) = pk;
      }
    }
  }
}

// ===== bf16 MFMA conv (smallws fallback, LDS weights) =====
template <int TX, int NP, int YB, bool POOL>
__global__ __launch_bounds__(256) void k_conv4(
    const short* __restrict__ in0, const short* __restrict__ in1,
    const float* __restrict__ w, const float* __restrict__ bias,
    const float* __restrict__ g, const float* __restrict__ bb,
    const float* __restrict__ m, const float* __restrict__ vv,
    short* __restrict__ out, int H) {
  constexpr int XT = TX + 2;
  constexpr int NR = (TX == 64) ? YB : 2;
  constexpr int YR = ((TX == 64) ? YB : 4) + 2;
  __shared__ short tile[YR * XT * 32];
  __shared__ short wlds[9216];
  __shared__ float sc[32], sh[32];
  int tid = threadIdx.x;
  int lane = tid & 63, wid = tid >> 6;
  int W = H;
  int b = blockIdx.z, y0 = blockIdx.y * ((TX == 64) ? YB : 4),
      x0 = blockIdx.x * TX;
  if (tid < 32) {
    float s = g[tid] * rsqrtf(vv[tid] + 1e-5f);
    sc[tid] = s;
    sh[tid] = (bias[tid] - m[tid]) * s + bb[tid];
  }
  int px = lane & 15, g4 = lane >> 4;
  int RB = (TX == 64) ? 0 : (wid >> 1) * 2;
  int wx = (TX == 64) ? wid : (wid & 1);
  f32x4 acc[NR][2];
#pragma unroll
  for (int r = 0; r < NR; ++r)
#pragma unroll
    for (int ct = 0; ct < 2; ++ct) acc[r][ct] = {0.f, 0.f, 0.f, 0.f};

  for (int cb = 0; cb < NP; ++cb) {
    if (cb) __syncthreads();
    for (int d = tid; d < 9216; d += 256) {
      int k = d & 7, l = (d >> 3) & 63, ct = (d >> 9) & 1, tap = d >> 10;
      int co = ct * 16 + (l & 15), cin = (l >> 4) * 8 + k;
      wlds[d] = f2b(w[(co * (NP * 32) + cb * 32 + cin) * 9 + tap]);
    }
    const short* in = cb ? in1 : in0;
    for (int i = tid; i < YR * XT * 4; i += 256) {
      int ir = i / (XT * 4), rem = i - ir * (XT * 4);
      int xl = rem >> 2, cg = rem & 3;
      int gy = y0 - 1 + ir, gx = x0 - 1 + xl;
      short8 v = {0, 0, 0, 0, 0, 0, 0, 0};
      if ((unsigned)gy < (unsigned)H && (unsigned)gx < (unsigned)W)
        v = *(const short8*)(in + (((size_t)(b * H + gy) * W + gx) << 5) +
                             cg * 8);
      *(short8*)&tile[(ir * XT + xl) * 32 +
                      ((cg ^ (xl & 3) ^ ((xl >> 2) & 3)) << 3)] = v;
    }
    __syncthreads();
    short8 wf[9][2];
#pragma unroll
    for (int tap = 0; tap < 9; ++tap)
#pragma unroll
      for (int ct = 0; ct < 2; ++ct)
        wf[tap][ct] = *(short8*)&wlds[(((tap * 2 + ct) << 6) + lane) << 3];
#pragma unroll
    for (int dx = 0; dx < 3; ++dx) {
      int xl = wx * 16 + px + dx;
      int cs = (g4 ^ (xl & 3) ^ ((xl >> 2) & 3)) << 3;
      short8 fr[NR + 2];
#pragma unroll
      for (int ir = 0; ir < NR + 2; ++ir)
        fr[ir] = *(short8*)&tile[((RB + ir) * XT + xl) * 32 + cs];
#pragma unroll
      for (int dy = 0; dy < 3; ++dy)
#pragma unroll
        for (int r = 0; r < NR; ++r)
#pragma unroll
          for (int ct = 0; ct < 2; ++ct)
            acc[r][ct] = __builtin_amdgcn_mfma_f32_16x16x32_bf16(
                wf[dy * 3 + dx][ct], fr[r + dy], acc[r][ct], 0, 0, 0);
    }
  }
  int xg = x0 + wx * 16 + px;
  if constexpr (POOL) {
    int H2 = H >> 1;
#pragma unroll
    for (int pr = 0; pr < NR / 2; ++pr) {
#pragma unroll
      for (int ct = 0; ct < 2; ++ct) {
        float o4[4];
#pragma unroll
        for (int q = 0; q < 4; ++q) {
          int co = ct * 16 + g4 * 4 + q;
          float v0 = acc[2 * pr][ct][q] * sc[co] + sh[co];
          float v1 = acc[2 * pr + 1][ct][q] * sc[co] + sh[co];
          v0 = v0 > 0.f ? v0 : 0.f;
          v1 = v1 > 0.f ? v1 : 0.f;
          float s2 = v0 + v1;
          o4[q] = 0.25f * (s2 + __shfl_xor(s2, 1, 64));
        }
        if (!(px & 1)) {
          int row = (y0 + RB + 2 * pr) >> 1;
          uint2 pk;
          pk.x = (unsigned)(unsigned short)f2b(o4[0]) |
                 ((unsigned)(unsigned short)f2b(o4[1]) << 16);
          pk.y = (unsigned)(unsigned short)f2b(o4[2]) |
                 ((unsigned)(unsigned short)f2b(o4[3]) << 16);
          size_t ob = (((size_t)(b * H2 + row) * H2 + (xg >> 1)) << 5) +
                      ct * 16 + g4 * 4;
          *(uint2*)(out + ob) = pk;
        }
      }
    }
  } else {
#pragma unroll
    for (int r = 0; r < NR; ++r) {
      int y = y0 + RB + r;
      size_t ob = (((size_t)(b * H + y) * W + xg) << 5);
#pragma unroll
      for (int ct = 0; ct < 2; ++ct) {
        uint2 pk;
        float o4[4];
#pragma unroll
        for (int q = 0; q < 4; ++q) {
          int co = ct * 16 + g4 * 4 + q;
          float val = acc[r][ct][q] * sc[co] + sh[co];
          o4[q] = val > 0.f ? val : 0.f;
        }
        pk.x = (unsigned)(unsigned short)f2b(o4[0]) |
               ((unsigned)(unsigned short)f2b(o4[1]) << 16);
        pk.y = (unsigned)(unsigned short)f2b(o4[2]) |
               ((unsigned)(unsigned short)f2b(o4[3]) << 16);
        *(uint2*)(out + ob + ct * 16 + g4 * 4) = pk;
      }
    }
  }
}

// ------- smallws front conv (writes fp32 NCHW feat directly) -------
__global__ __launch_bounds__(256) void k_conv_front(
    const float* __restrict__ x, const float* __restrict__ xf,
    const float* __restrict__ w_spa, const float* __restrict__ b_spa,
    const float* __restrict__ w_fre, const float* __restrict__ b_fre,
    const float* __restrict__ g, const float* __restrict__ bb,
    const float* __restrict__ m, const float* __restrict__ vv,
    float* __restrict__ feat) {
  int z = blockIdx.z;
  const float* in = z ? xf : x;
  const float* w = z ? w_fre : w_spa;
  const float* bias = z ? b_fre : b_spa;
  __shared__ float wl[864];
  __shared__ float sc[32], sh[32];
  int tid = threadIdx.x;
  for (int i = tid; i < 864; i += 256) wl[i] = w[i];
  if (tid < 32) {
    int cg = z * 32 + tid;
    float s = g[cg] * rsqrtf(vv[cg] + 1e-5f);
    sc[tid] = s;
    sh[tid] = (bias[tid] - m[cg]) * s + bb[cg];
  }
  __syncthreads();
  int b = blockIdx.y;
  int idx = blockIdx.x * 256 + tid;
  int ry = idx >> 8;
  int xx = idx & 255;
  int y0 = ry * 2;
  const float* inb = in + (size_t)b * 3 * 65536;
  float a0[32], a1[32];
#pragma unroll
  for (int co = 0; co < 32; ++co) {
    a0[co] = 0.f;
    a1[co] = 0.f;
  }
  for (int ci = 0; ci < 3; ++ci) {
    const float* p = inb + (size_t)ci * 65536;
    float v[4][3];
#pragma unroll
    for (int r = 0; r < 4; ++r) {
      int iy = y0 + r - 1;
      bool yok = (unsigned)iy < 256u;
#pragma unroll
      for (int c = 0; c < 3; ++c) {
        int ix = xx + c - 1;
        v[r][c] = (yok && (unsigned)ix < 256u) ? p[iy * 256 + ix] : 0.f;
      }
    }
#pragma unroll
    for (int t9 = 0; t9 < 9; ++t9) {
      int ky = t9 / 3, kx = t9 % 3;
      float v0 = v[ky][kx], v1 = v[ky + 1][kx];
#pragma unroll
      for (int co = 0; co < 32; ++co) {
        float wv = wl[co * 27 + ci * 9 + t9];
        a0[co] = fmaf(v0, wv, a0[co]);
        a1[co] = fmaf(v1, wv, a1[co]);
      }
    }
  }
#pragma unroll
  for (int co = 0; co < 32; ++co) {
    size_t o = ((size_t)(b * 64 + z * 32 + co) * 256 + y0) * 256 + xx;
    float r0 = a0[co] * sc[co] + sh[co];
    float r1 = a1[co] * sc[co] + sh[co];
    feat[o] = r0 > 0.f ? r0 : 0.f;
    feat[o + 256] = r1 > 0.f ? r1 : 0.f;
  }
}

// ---------------- smallws L1: 64ch fp32 NCHW gather ----------
__global__ __launch_bounds__(256) void k_conv1_mfma(
    const float* __restrict__ in, const float* __restrict__ w,
    const float* __restrict__ bias, const float* __restrict__ g,
    const float* __restrict__ bb, const float* __restrict__ m,
    const float* __restrict__ vv, short* __restrict__ out) {
  constexpr int TX = 64, XT = 66;
  __shared__ short tile[4 * XT * 64];
  __shared__ short wlds[9216];
  __shared__ float sc[32], sh[32];
  int tid = threadIdx.x;
  int lane = tid & 63, wid = tid >> 6;
  int b = blockIdx.z, y0 = blockIdx.y * 2, x0 = blockIdx.x * TX;
  if (tid < 32) {
    float s = g[tid] * rsqrtf(vv[tid] + 1e-5f);
    sc[tid] = s;
    sh[tid] = (bias[tid] - m[tid]) * s + bb[tid];
  }
  for (int ir = 0; ir < 4; ++ir) {
    int gy = y0 - 1 + ir;
    bool yok = (unsigned)gy < 256u;
    for (int ch = tid; ch < XT * 8; ch += 256) {
      int xl = ch >> 3, cg = ch & 7;
      int gx = x0 - 1 + xl;
      short8 v = {0, 0, 0, 0, 0, 0, 0, 0};
      if (yok && (unsigned)gx < 256u) {
        const float* p = in + (((size_t)(b * 64 + cg * 8)) << 16) + (gy << 8) + gx;
#pragma unroll
        for (int k = 0; k < 8; ++k) v[k] = f2b(p[(size_t)k << 16]);
      }
      *(short8*)&tile[((ir * XT + xl) << 6) + ((cg ^ (xl & 7)) << 3)] = v;
    }
  }
  int px = lane & 15, g4 = lane >> 4;
  int wx = wid;
  f32x4 acc[2][2];
#pragma unroll
  for (int r = 0; r < 2; ++r)
#pragma unroll
    for (int ct = 0; ct < 2; ++ct) acc[r][ct] = {0.f, 0.f, 0.f, 0.f};
  for (int cb = 0; cb < 2; ++cb) {
    __syncthreads();
    for (int d = tid; d < 9216; d += 256) {
      int k = d & 7, l = (d >> 3) & 63, ct = (d >> 9) & 1, tap = d >> 10;
      int co = ct * 16 + (l & 15), cin = (l >> 4) * 8 + k;
      wlds[d] = f2b(w[(co * 64 + cb * 32 + cin) * 9 + tap]);
    }
    __syncthreads();
    short8 wf[9][2];
#pragma unroll
    for (int tap = 0; tap < 9; ++tap)
#pragma unroll
      for (int ct = 0; ct < 2; ++ct)
        wf[tap][ct] = *(short8*)&wlds[(((tap * 2 + ct) << 6) + lane) << 3];
#pragma unroll
    for (int dx = 0; dx < 3; ++dx) {
      short8 fr[4];
#pragma unroll
      for (int ir = 0; ir < 4; ++ir) {
        int xl = wx * 16 + px + dx;
        fr[ir] = *(short8*)&tile[((ir * XT + xl) << 6) +
                                 (((cb * 4 + g4) ^ (xl & 7)) << 3)];
      }
#pragma unroll
      for (int dy = 0; dy < 3; ++dy)
#pragma unroll
        for (int r = 0; r < 2; ++r)
#pragma unroll
          for (int ct = 0; ct < 2; ++ct)
            acc[r][ct] = __builtin_amdgcn_mfma_f32_16x16x32_bf16(
                wf[dy * 3 + dx][ct], fr[r + dy], acc[r][ct], 0, 0, 0);
    }
  }
#pragma unroll
  for (int r = 0; r < 2; ++r) {
    int y = y0 + r;
    int xg = x0 + wx * 16 + px;
    size_t ob = (((size_t)(b * 256 + y) * 256 + xg) << 5);
#pragma unroll
    for (int ct = 0; ct < 2; ++ct) {
      unsigned short u[4];
#pragma unroll
      for (int q = 0; q < 4; ++q) {
        int co = ct * 16 + g4 * 4 + q;
        float val = acc[r][ct][q] * sc[co] + sh[co];
        val = val > 0.f ? val : 0.f;
        u[q] = (unsigned short)f2b(val);
      }
      uint2 pk;
      pk.x = (unsigned)u[0] | ((unsigned)u[1] << 16);
      pk.y = (unsigned)u[2] | ((unsigned)u[3] << 16);
      *(uint2*)(out + ob + ct * 16 + g4 * 4) = pk;
    }
  }
}

// ===== fused tail: L9 + L10 (@32, in LDS) + global mean + fc, one block/batch ==
template <bool F8>
__global__ __launch_bounds__(256) void k_tail(
    const void* __restrict__ in, const float* __restrict__ w9,
    const float* __restrict__ b9, const float* __restrict__ w10,
    const float* __restrict__ b10, const float* __restrict__ cg9,
    const float* __restrict__ cb9, const float* __restrict__ cm9,
    const float* __restrict__ cv9, const float* __restrict__ cg10,
    const float* __restrict__ cb10, const float* __restrict__ cm10,
    const float* __restrict__ cv10, const float* __restrict__ fw,
    const float* __restrict__ fb, float* __restrict__ logits) {
  __shared__ short tileA[32768];
  __shared__ short tileB[32768];
  __shared__ short wlds[9216];
  __shared__ float sc[2][32], sh[2][32];
  __shared__ float red[16][8];
  __shared__ float smean[32];
  int tid = threadIdx.x;
  int lane = tid & 63, wv = tid >> 6;
  int b = blockIdx.x;
  int px = lane & 15, g4 = lane >> 4;

  if (tid < 64) {
    int l = tid >> 5, c = tid & 31;
    const float* g = l ? cg10 : cg9;
    const float* bb = l ? cb10 : cb9;
    const float* m = l ? cm10 : cm9;
    const float* v = l ? cv10 : cv9;
    const float* bi = l ? b10 : b9;
    float s = g[c] * rsqrtf(v[c] + 1e-5f);
    sc[l][c] = s;
    sh[l][c] = (bi[c] - m[c]) * s + bb[c];
  }
  if constexpr (F8) {
    const uchar* src = (const uchar*)in + (size_t)b * 32768;
    for (int i = tid; i < 2048; i += 256) {
      int p = i >> 1, c2 = i & 1, xc = p & 31;
      uint4v raw = *(const uint4v*)(src + p * 32 + c2 * 16);
      float f[16];
      upk4(raw[0], f + 0);
      upk4(raw[1], f + 4);
      upk4(raw[2], f + 8);
      upk4(raw[3], f + 12);
      short8 o0, o1;
#pragma unroll
      for (int k = 0; k < 8; ++k) {
        o0[k] = f2b(f[k]);
        o1[k] = f2b(f[k + 8]);
      }
      int sw = (xc & 3) ^ ((xc >> 2) & 3);
      *(short8*)&tileA[p * 32 + (((c2 * 2) ^ sw) << 3)] = o0;
      *(short8*)&tileA[p * 32 + (((c2 * 2 + 1) ^ sw) << 3)] = o1;
    }
  } else {
    const short* src = (const short*)in + (size_t)b * 32768;
    for (int i = tid; i < 4096; i += 256) {
      int p = i >> 2, cg = i & 3;
      int xc = p & 31;
      short8 v = *(const short8*)(src + p * 32 + cg * 8);
      *(short8*)&tileA[p * 32 + ((cg ^ (xc & 3) ^ ((xc >> 2) & 3)) << 3)] = v;
    }
  }
  float psum[2][4];
#pragma unroll
  for (int ct = 0; ct < 2; ++ct)
#pragma unroll
    for (int q = 0; q < 4; ++q) psum[ct][q] = 0.f;

  for (int layer = 0; layer < 2; ++layer) {
    if (layer) __syncthreads();
    const float* w = layer ? w10 : w9;
    for (int d = tid; d < 9216; d += 256) {
      int k = d & 7, l = (d >> 3) & 63, ct = (d >> 9) & 1, tap = d >> 10;
      int co = ct * 16 + (l & 15), cin = (l >> 4) * 8 + k;
      wlds[d] = f2b(w[(co * 32 + cin) * 9 + tap]);
    }
    __syncthreads();
    short8 wf[9][2];
#pragma unroll
    for (int tap = 0; tap < 9; ++tap)
#pragma unroll
      for (int ct = 0; ct < 2; ++ct)
        wf[tap][ct] = *(short8*)&wlds[(((tap * 2 + ct) << 6) + lane) << 3];
    const short* ts = layer ? tileB : tileA;
    for (int u = wv; u < 16; u += 4) {
      int rw = u >> 1, cw = u & 1;
      f32x4 acc[4][2];
#pragma unroll
      for (int r = 0; r < 4; ++r)
#pragma unroll
        for (int ct = 0; ct < 2; ++ct) acc[r][ct] = {0.f, 0.f, 0.f, 0.f};
#pragma unroll
      for (int dx = 0; dx < 3; ++dx) {
        int gx = cw * 16 + px + dx - 1;
        bool xok = (unsigned)gx < 32u;
        int cs = (g4 ^ (gx & 3) ^ ((gx >> 2) & 3)) << 3;
        short8 fr[6];
        short8 zz = {0, 0, 0, 0, 0, 0, 0, 0};
#pragma unroll
        for (int ir = 0; ir < 6; ++ir) {
          int gy = rw * 4 + ir - 1;
          fr[ir] = (xok && (unsigned)gy < 32u)
                       ? *(const short8*)&ts[(gy * 32 + gx) * 32 + cs]
                       : zz;
        }
#pragma unroll
        for (int dy = 0; dy < 3; ++dy)
#pragma unroll
          for (int r = 0; r < 4; ++r)
#pragma unroll
            for (int ct = 0; ct < 2; ++ct)
              acc[r][ct] = __builtin_amdgcn_mfma_f32_16x16x32_bf16(
                  wf[dy * 3 + dx][ct], fr[r + dy], acc[r][ct], 0, 0, 0);
      }
      int xc = cw * 16 + px;
#pragma unroll
      for (int r = 0; r < 4; ++r) {
        int y = rw * 4 + r;
#pragma unroll
        for (int ct = 0; ct < 2; ++ct) {
          float v4[4];
#pragma unroll
          for (int q = 0; q < 4; ++q) {
            int co = ct * 16 + g4 * 4 + q;
            float val = acc[r][ct][q] * sc[layer][co] + sh[layer][co];
            v4[q] = val > 0.f ? val : 0.f;
          }
          if (layer == 0) {
            int cg = ct * 2 + (g4 >> 1);
            int scg = cg ^ (xc & 3) ^ ((xc >> 2) & 3);
            uint2 pk;
            pk.x = (unsigned)(unsigned short)f2b(v4[0]) |
                   ((unsigned)(unsigned short)f2b(v4[1]) << 16);
            pk.y = (unsigned)(unsigned short)f2b(v4[2]) |
                   ((unsigned)(unsigned short)f2b(v4[3]) << 16);
            *(uint2*)&tileB[(y * 32 + xc) * 32 + (scg << 3) + (g4 & 1) * 4] = pk;
          } else {
#pragma unroll
            for (int q = 0; q < 4; ++q) psum[ct][q] += v4[q];
          }
        }
      }
    }
  }
#pragma unroll
  for (int o = 1; o < 16; o <<= 1)
#pragma unroll
    for (int ct = 0; ct < 2; ++ct)
#pragma unroll
      for (int q = 0; q < 4; ++q)
        psum[ct][q] += __shfl_xor(psum[ct][q], o, 64);
  if (px == 0) {
#pragma unroll
    for (int ct = 0; ct < 2; ++ct)
#pragma unroll
      for (int q = 0; q < 4; ++q) red[wv * 4 + g4][ct * 4 + q] = psum[ct][q];
  }
  __syncthreads();
  if (tid < 32) {
    int ct = tid >> 4, g4r = (tid >> 2) & 3, q = tid & 3;
    float s = red[g4r][ct * 4 + q] + red[4 + g4r][ct * 4 + q] +
              red[8 + g4r][ct * 4 + q] + red[12 + g4r][ct * 4 + q];
    smean[tid] = s * (1.f / 1024.f);
  }
  __syncthreads();
  if (tid < 2) {
    float s = fb[tid];
    for (int c = 0; c < 32; ++c) s = fmaf(smean[c], fw[tid * 32 + c], s);
    logits[b * 2 + tid] = s;
  }
}

extern "C" void kernel_launch(void* const* d_in, const int* in_sizes, int n_in,
                              void* d_out, int out_size, void* d_ws,
                              size_t ws_size, hipStream_t stream) {
  const float* x = (const float*)d_in[0];
  const float* dmean = (const float*)d_in[1];
  const float* dstd = (const float*)d_in[2];
  const float* w_spa = (const float*)d_in[3];
  const float* b_spa = (const float*)d_in[4];
  const float* w_fre = (const float*)d_in[5];
  const float* b_fre = (const float*)d_in[6];
  const float* bn0_g = (const float*)d_in[7];
  const float* bn0_b = (const float*)d_in[8];
  const float* bn0_m = (const float*)d_in[9];
  const float* bn0_v = (const float*)d_in[10];
  const float* cls_w1 = (const float*)d_in[11];
  const float* cls_b1 = (const float*)d_in[12];
  const float* cls_w = (const float*)d_in[13];
  const float* cls_b = (const float*)d_in[14];
  const float* cbn_g = (const float*)d_in[15];
  const float* cbn_b = (const float*)d_in[16];
  const float* cbn_m = (const float*)d_in[17];
  const float* cbn_v = (const float*)d_in[18];
  const float* fc_w = (const float*)d_in[19];
  const float* fc_b = (const float*)d_in[20];

  float* out = (float*)d_out;
  float* logits = out;     // [16,2] fp32
  float* feat = out + 32;  // [16,64,256,256] fp32 NCHW

  char* ws = (char*)d_ws;
  const size_t MB = 1048576ull;
  bool bigws = ws_size >= 193ull * MB;

  const int WS = 32 * 32 * 9;
  if (bigws) {
    uchar* featN0 = (uchar*)ws;              // 32 MiB fp8 plane z=0
    uchar* featN1 = (uchar*)(ws + 32 * MB);  // 32 MiB fp8 plane z=1
    uchar* bufA = (uchar*)(ws + 64 * MB);    // 32 MiB fp8
    uchar* bufB = (uchar*)ws;                // aliases featN0 (dead after L1)
    uchar* wpack = (uchar*)(ws + 192 * MB);  // 9 sets x 9216 fp8 bytes
    float* D = (float*)(ws + 96 * MB);
    float* M1 = (float*)(ws + 97 * MB);
    float* xf = (float*)(ws + 112 * MB);

    k_init<<<dim3(265), dim3(256), 0, stream>>>(D, cls_w1, cls_w, wpack);
    k_dct1<<<dim3(4, 4, 48), dim3(256), 0, stream>>>(D, x, M1);
    k_dct2<<<dim3(4, 4, 48), dim3(256), 0, stream>>>(M1, D, dmean, dstd, xf);

    k_front_n<<<dim3(128, 16, 2), dim3(256), 0, stream>>>(
        x, xf, w_spa, b_spa, w_fre, b_fre, bn0_g, bn0_b, bn0_m, bn0_v, featN0,
        featN1, feat);
    // L1 (64->32) YB=8, fp8-native MFMA
    k_conv8<64, 2, 8, false><<<dim3(4, 32, 16), dim3(256), 0, stream>>>(
        featN0, featN1, wpack, cls_b1, cbn_g, cbn_b, cbn_m, cbn_v, bufA, 256);
    // L2..L4 @256
    k_conv8<64, 1, 8, false><<<dim3(4, 32, 16), dim3(256), 0, stream>>>(
        bufA, nullptr, wpack + 2 * 9216, cls_b + 0 * 32, cbn_g + 32,
        cbn_b + 32, cbn_m + 32, cbn_v + 32, bufB, 256);
    k_conv8<64, 1, 8, false><<<dim3(4, 32, 16), dim3(256), 0, stream>>>(
        bufB, nullptr, wpack + 3 * 9216, cls_b + 1 * 32, cbn_g + 64,
        cbn_b + 64, cbn_m + 64, cbn_v + 64, bufA, 256);
    k_conv8<64, 1, 8, true><<<dim3(4, 32, 16), dim3(256), 0, stream>>>(
        bufA, nullptr, wpack + 4 * 9216, cls_b + 2 * 32, cbn_g + 96,
        cbn_b + 96, cbn_m + 96, cbn_v + 96, bufB, 256);
    // L5,L6 @128
    k_conv8<64, 1, 8, false><<<dim3(2, 16, 16), dim3(256), 0, stream>>>(
        bufB, nullptr, wpack + 5 * 9216, cls_b + 3 * 32, cbn_g + 128,
        cbn_b + 128, cbn_m + 128, cbn_v + 128, bufA, 128);
    k_conv8<64, 1, 8, true><<<dim3(2, 16, 16), dim3(256), 0, stream>>>(
        bufA, nullptr, wpack + 6 * 9216, cls_b + 4 * 32, cbn_g + 160,
        cbn_b + 160, cbn_m + 160, cbn_v + 160, bufB, 128);
    // L7,L8 @64 (TX=32)
    k_conv8<32, 1, 4, false><<<dim3(2, 16, 16), dim3(256), 0, stream>>>(
        bufB, nullptr, wpack + 7 * 9216, cls_b + 5 * 32, cbn_g + 192,
        cbn_b + 192, cbn_m + 192, cbn_v + 192, bufA, 64);
    k_conv8<32, 1, 4, true><<<dim3(2, 16, 16), dim3(256), 0, stream>>>(
        bufA, nullptr, wpack + 8 * 9216, cls_b + 6 * 32, cbn_g + 224,
        cbn_b + 224, cbn_m + 224, cbn_v + 224, bufB, 64);
    k_tail<true><<<dim3(16), dim3(256), 0, stream>>>(
        bufB, cls_w + 7 * WS, cls_b + 7 * 32, cls_w + 8 * WS, cls_b + 8 * 32,
        cbn_g + 256, cbn_b + 256, cbn_m + 256, cbn_v + 256, cbn_g + 288,
        cbn_b + 288, cbn_m + 288, cbn_v + 288, fc_w, fc_b, logits);
  } else {
    short* bufA = (short*)ws;
    short* bufB = (short*)(ws + 64 * MB);
    float* D = (float*)ws;
    float* M1 = (float*)(ws + 1 * MB);
    float* xf = (float*)(ws + 64 * MB);

    k_build_dct<<<dim3(256), dim3(256), 0, stream>>>(D);
    k_dct1<<<dim3(4, 4, 48), dim3(256), 0, stream>>>(D, x, M1);
    k_dct2<<<dim3(4, 4, 48), dim3(256), 0, stream>>>(M1, D, dmean, dstd, xf);
    k_conv_front<<<dim3(128, 16, 2), dim3(256), 0, stream>>>(
        x, xf, w_spa, b_spa, w_fre, b_fre, bn0_g, bn0_b, bn0_m, bn0_v, feat);
    k_conv1_mfma<<<dim3(4, 128, 16), dim3(256), 0, stream>>>(
        feat, cls_w1, cls_b1, cbn_g, cbn_b, cbn_m, cbn_v, bufA);
    k_conv4<64, 1, 8, false><<<dim3(4, 32, 16), dim3(256), 0, stream>>>(
        bufA, nullptr, cls_w + 0 * WS, cls_b + 0 * 32, cbn_g + 32, cbn_b + 32,
        cbn_m + 32, cbn_v + 32, bufB, 256);
    k_conv4<64, 1, 8, false><<<dim3(4, 32, 16), dim3(256), 0, stream>>>(
        bufB, nullptr, cls_w + 1 * WS, cls_b + 1 * 32, cbn_g + 64, cbn_b + 64,
        cbn_m + 64, cbn_v + 64, bufA, 256);
    k_conv4<64, 1, 8, true><<<dim3(4, 32, 16), dim3(256), 0, stream>>>(
        bufA, nullptr, cls_w + 2 * WS, cls_b + 2 * 32, cbn_g + 96, cbn_b + 96,
        cbn_m + 96, cbn_v + 96, bufB, 256);
    k_conv4<64, 1, 8, false><<<dim3(2, 16, 16), dim3(256), 0, stream>>>(
        bufB, nullptr, cls_w + 3 * WS, cls_b + 3 * 32, cbn_g + 128,
        cbn_b + 128, cbn_m + 128, cbn_v + 128, bufA, 128);
    k_conv4<64, 1, 8, true><<<dim3(2, 16, 16), dim3(256), 0, stream>>>(
        bufA, nullptr, cls_w + 4 * WS, cls_b + 4 * 32, cbn_g + 160,
        cbn_b + 160, cbn_m + 160, cbn_v + 160, bufB, 128);
    k_conv4<32, 1, 4, false><<<dim3(2, 16, 16), dim3(256), 0, stream>>>(
        bufB, nullptr, cls_w + 5 * WS, cls_b + 5 * 32, cbn_g + 192,
        cbn_b + 192, cbn_m + 192, cbn_v + 192, bufA, 64);
    k_conv4<32, 1, 4, true><<<dim3(2, 16, 16), dim3(256), 0, stream>>>(
        bufA, nullptr, cls_w + 6 * WS, cls_b + 6 * 32, cbn_g + 224,
        cbn_b + 224, cbn_m + 224, cbn_v + 224, bufB, 64);
    k_tail<false><<<dim3(16), dim3(256), 0, stream>>>(
        bufB, cls_w + 7 * WS, cls_b + 7 * 32, cls_w + 8 * WS, cls_b + 8 * 32,
        cbn_g + 256, cbn_b + 256, cbn_m + 256, cbn_v + 256, cbn_g + 288,
        cbn_b + 288, cbn_m + 288, cbn_v + 288, fc_w, fc_b, logits);
  }
}

// Round 22
// 327.801 us; speedup vs baseline: 1.0576x; 1.0576x over previous
//
#include <hip/hip_runtime.h>
#include <hip/hip_bf16.h>
#include <hip/hip_fp8.h>
#include <math.h>

typedef __hip_bfloat16 bf16;
typedef unsigned char uchar;
typedef unsigned long long u64;
typedef __attribute__((ext_vector_type(8))) short short8;
typedef __attribute__((ext_vector_type(4))) float f32x4;
typedef __attribute__((ext_vector_type(2))) float f32x2;
typedef __attribute__((ext_vector_type(4))) unsigned uint4v;
typedef __attribute__((ext_vector_type(2))) u64 u64x2;

__device__ __forceinline__ float b2f(short s) {
  unsigned u = ((unsigned)(unsigned short)s) << 16;
  return __builtin_bit_cast(float, u);
}
__device__ __forceinline__ short f2b(float f) {
  bf16 h = __float2bfloat16(f);
  return *reinterpret_cast<short*>(&h);
}

#if defined(__has_builtin)
#if __has_builtin(__builtin_amdgcn_cvt_pk_fp8_f32) && \
    __has_builtin(__builtin_amdgcn_cvt_pk_f32_fp8)
#define HWFP8 1
#endif
#endif

#ifdef HWFP8
__device__ __forceinline__ unsigned pk4q(float a, float b, float c, float d) {
  int r = __builtin_amdgcn_cvt_pk_fp8_f32(a, b, 0, false);
  r = __builtin_amdgcn_cvt_pk_fp8_f32(c, d, r, true);
  return (unsigned)r;
}
__device__ __forceinline__ void upk4(unsigned w, float* o) {
  f32x2 lo = __builtin_amdgcn_cvt_pk_f32_fp8((int)w, false);
  f32x2 hi = __builtin_amdgcn_cvt_pk_f32_fp8((int)w, true);
  o[0] = lo[0];
  o[1] = lo[1];
  o[2] = hi[0];
  o[3] = hi[1];
}
#else
__device__ __forceinline__ uchar f2q_(float f) {
  __hip_fp8_e4m3 t(f);
  return (uchar)t.__x;
}
__device__ __forceinline__ float q2f_(uchar c) {
  __hip_fp8_e4m3 t;
  t.__x = (__hip_fp8_storage_t)c;
  return (float)t;
}
__device__ __forceinline__ unsigned pk4q(float a, float b, float c, float d) {
  return (unsigned)f2q_(a) | ((unsigned)f2q_(b) << 8) |
         ((unsigned)f2q_(c) << 16) | ((unsigned)f2q_(d) << 24);
}
__device__ __forceinline__ void upk4(unsigned w, float* o) {
  o[0] = q2f_((uchar)(w & 255));
  o[1] = q2f_((uchar)((w >> 8) & 255));
  o[2] = q2f_((uchar)((w >> 16) & 255));
  o[3] = q2f_((uchar)((w >> 24) & 255));
}
#endif

// ---------------- smallws helper: DCT matrix only ----------------
__global__ void k_build_dct(float* __restrict__ D) {
  int k = blockIdx.x, i = threadIdx.x;
  double v = cos(3.14159265358979323846 * (2.0 * i + 1.0) * (double)k / 512.0) *
             0.08838834764831845;
  if (k == 0) v *= 0.7071067811865476;
  D[k * 256 + i] = (float)v;
}

// ---- merged init (bigws): blocks 0..255 build DCT; 256..264 pack fp8 weights --
__global__ void k_init(float* __restrict__ D, const float* __restrict__ w1,
                       const float* __restrict__ wc, uchar* __restrict__ wp) {
  int blk = blockIdx.x;
  if (blk < 256) {
    int k = blk, i = threadIdx.x;
    double v = cos(3.14159265358979323846 * (2.0 * i + 1.0) * (double)k /
                   512.0) *
               0.08838834764831845;
    if (k == 0) v *= 0.7071067811865476;
    D[k * 256 + i] = (float)v;
  } else {
    int set = blk - 256;
    const float* w;
    int C, cbase;
    if (set < 2) {
      w = w1;
      C = 64;
      cbase = set * 32;
    } else {
      w = wc + (set - 2) * 9216;
      C = 32;
      cbase = 0;
    }
    for (int d4 = threadIdx.x; d4 < 2304; d4 += 256) {
      float f[4];
#pragma unroll
      for (int j = 0; j < 4; ++j) {
        int d = d4 * 4 + j;
        int k = d & 7, l = (d >> 3) & 63, ct = (d >> 9) & 1, tap = d >> 10;
        int co = ct * 16 + (l & 15), cin = (l >> 4) * 8 + k;
        f[j] = w[(co * C + cbase + cin) * 9 + tap];
      }
      *(unsigned*)(wp + set * 9216 + d4 * 4) = pk4q(f[0], f[1], f[2], f[3]);
    }
  }
}

// ---- stage1: M1 = D @ X, fp32, k-ascending single accumulator (BLAS order) ----
__global__ __launch_bounds__(256) void k_dct1(const float* __restrict__ D,
                                              const float* __restrict__ x,
                                              float* __restrict__ M1) {
  __shared__ __align__(16) float As[32][84];
  __shared__ __align__(16) float Bs[32][80];
  int tid = threadIdx.x;
  int tx = tid & 15, ty = tid >> 4;
  int k0 = blockIdx.x * 64, i0 = blockIdx.y * 64;
  size_t base = (size_t)blockIdx.z * 65536;
  float acc[4][4];
#pragma unroll
  for (int a = 0; a < 4; ++a)
#pragma unroll
    for (int c = 0; c < 4; ++c) acc[a][c] = 0.f;
  for (int kk = 0; kk < 256; kk += 32) {
    __syncthreads();
#pragma unroll
    for (int s = 0; s < 2; ++s) {
      int idx = s * 256 + tid;
      int i = idx >> 3, k4 = (idx & 7) * 4;
      f32x4 d4 = *(const f32x4*)&D[(i0 + i) * 256 + kk + k4];
#pragma unroll
      for (int q = 0; q < 4; ++q) As[k4 + q][i] = d4[q];
      int j = idx >> 4, c4 = (idx & 15) * 4;
      *(f32x4*)&Bs[j][c4] =
          *(const f32x4*)&x[base + (size_t)(kk + j) * 256 + k0 + c4];
    }
    __syncthreads();
#pragma unroll
    for (int k = 0; k < 32; ++k) {
      f32x4 a4 = *(const f32x4*)&As[k][ty * 4];
      f32x4 b4 = *(const f32x4*)&Bs[k][tx * 4];
#pragma unroll
      for (int ii = 0; ii < 4; ++ii)
#pragma unroll
        for (int jj = 0; jj < 4; ++jj)
          acc[ii][jj] = fmaf(a4[ii], b4[jj], acc[ii][jj]);
    }
  }
#pragma unroll
  for (int ii = 0; ii < 4; ++ii) {
    f32x4 o = {acc[ii][0], acc[ii][1], acc[ii][2], acc[ii][3]};
    *(f32x4*)&M1[base + (size_t)(i0 + ty * 4 + ii) * 256 + k0 + tx * 4] = o;
  }
}

// ---- stage2: xf = lognorm(M1 @ D^T) ----
__global__ __launch_bounds__(256) void k_dct2(const float* __restrict__ M1,
                                              const float* __restrict__ D,
                                              const float* __restrict__ dmean,
                                              const float* __restrict__ dstd,
                                              float* __restrict__ xf) {
  __shared__ __align__(16) float As[32][84];
  __shared__ __align__(16) float Bs[32][84];
  int tid = threadIdx.x;
  int tx = tid & 15, ty = tid >> 4;
  int l0 = blockIdx.x * 64, i0 = blockIdx.y * 64;
  int bc = blockIdx.z;
  size_t base = (size_t)bc * 65536;
  int ch = bc % 3;
  float acc[4][4];
#pragma unroll
  for (int a = 0; a < 4; ++a)
#pragma unroll
    for (int c = 0; c < 4; ++c) acc[a][c] = 0.f;
  for (int kk = 0; kk < 256; kk += 32) {
    __syncthreads();
#pragma unroll
    for (int s = 0; s < 2; ++s) {
      int idx = s * 256 + tid;
      int i = idx >> 3, k4 = (idx & 7) * 4;
      f32x4 a4 = *(const f32x4*)&M1[base + (size_t)(i0 + i) * 256 + kk + k4];
      f32x4 b4 = *(const f32x4*)&D[(l0 + i) * 256 + kk + k4];
#pragma unroll
      for (int q = 0; q < 4; ++q) {
        As[k4 + q][i] = a4[q];
        Bs[k4 + q][i] = b4[q];
      }
    }
    __syncthreads();
#pragma unroll
    for (int k = 0; k < 32; ++k) {
      f32x4 a4 = *(const f32x4*)&As[k][ty * 4];
      f32x4 b4 = *(const f32x4*)&Bs[k][tx * 4];
#pragma unroll
      for (int ii = 0; ii < 4; ++ii)
#pragma unroll
        for (int jj = 0; jj < 4; ++jj)
          acc[ii][jj] = fmaf(a4[ii], b4[jj], acc[ii][jj]);
    }
  }
#pragma unroll
  for (int ii = 0; ii < 4; ++ii) {
    int ig = i0 + ty * 4 + ii;
    int ll = l0 + tx * 4;
    int mi = (ch * 256 + ig) * 256 + ll;
    f32x4 dm = *(const f32x4*)&dmean[mi];
    f32x4 ds = *(const f32x4*)&dstd[mi];
    f32x4 o;
#pragma unroll
    for (int jj = 0; jj < 4; ++jj)
      o[jj] = (logf(fabsf(acc[ii][jj]) + 1e-13f) - dm[jj]) / ds[jj];
    *(f32x4*)&xf[base + (size_t)ig * 256 + ll] = o;
  }
}

// ------- front conv (bigws): 3->32 both branches + bn0 + relu
//   -> NHWC32 fp8 planes (LDS-bounced) + fp32 NCHW feat (NT, registers)
__global__ __launch_bounds__(256) void k_front_n(
    const float* __restrict__ x, const float* __restrict__ xf,
    const float* __restrict__ w_spa, const float* __restrict__ b_spa,
    const float* __restrict__ w_fre, const float* __restrict__ b_fre,
    const float* __restrict__ g, const float* __restrict__ bb,
    const float* __restrict__ m, const float* __restrict__ vv,
    uchar* __restrict__ featN0, uchar* __restrict__ featN1,
    float* __restrict__ feat) {
  __shared__ __align__(16) float xin[3 * 4 * 264];
  __shared__ __align__(16) short fstage[2 * 256 * 32];
  __shared__ float wl[864];
  __shared__ float sc[32], sh[32];
  int z = blockIdx.z;
  const float* in = z ? xf : x;
  const float* w = z ? w_fre : w_spa;
  const float* bias = z ? b_fre : b_spa;
  int tid = threadIdx.x;
  int b = blockIdx.y;
  int y0 = blockIdx.x * 2;
  for (int i = tid; i < 864; i += 256) wl[i] = w[i];
  if (tid < 32) {
    int cgl = z * 32 + tid;
    float s = g[cgl] * rsqrtf(vv[cgl] + 1e-5f);
    sc[tid] = s;
    sh[tid] = (bias[tid] - m[cgl]) * s + bb[cgl];
  }
  const float* inb = in + (size_t)b * 3 * 65536;
  for (int i = tid; i < 792; i += 256) {
    int ci = i / 264, rem = i - ci * 264;
    int r = rem / 66, c = rem - r * 66;
    int gy = y0 - 1 + r;
    f32x4 v = {0.f, 0.f, 0.f, 0.f};
    if ((unsigned)gy < 256u && c >= 1 && c <= 64)
      v = *(const f32x4*)&inb[((size_t)ci << 16) + (gy << 8) + (c * 4 - 4)];
    *(f32x4*)&xin[(ci * 4 + r) * 264 + c * 4] = v;
  }
  __syncthreads();
  int xq = tid & 63, cg = tid >> 6;
  int x0 = xq * 4;
  float acc[2][4][8];
#pragma unroll
  for (int r = 0; r < 2; ++r)
#pragma unroll
    for (int p = 0; p < 4; ++p)
#pragma unroll
      for (int co = 0; co < 8; ++co) acc[r][p][co] = 0.f;
  for (int ci = 0; ci < 3; ++ci) {
    float v[4][6];
#pragma unroll
    for (int r = 0; r < 4; ++r) {
      const float* row = &xin[(ci * 4 + r) * 264];
      f32x4 qA = *(const f32x4*)&row[x0];
      f32x4 qB = *(const f32x4*)&row[x0 + 4];
      f32x4 qC = *(const f32x4*)&row[x0 + 8];
      v[r][0] = qA[3];
      v[r][1] = qB[0];
      v[r][2] = qB[1];
      v[r][3] = qB[2];
      v[r][4] = qB[3];
      v[r][5] = qC[0];
    }
#pragma unroll
    for (int co = 0; co < 8; ++co) {
      int cob = cg * 8 + co;
      float w9[9];
#pragma unroll
      for (int t = 0; t < 9; ++t) w9[t] = wl[cob * 27 + ci * 9 + t];
#pragma unroll
      for (int ky = 0; ky < 3; ++ky)
#pragma unroll
        for (int kx = 0; kx < 3; ++kx) {
          float wv = w9[ky * 3 + kx];
#pragma unroll
          for (int r = 0; r < 2; ++r)
#pragma unroll
            for (int p = 0; p < 4; ++p)
              acc[r][p][co] = fmaf(v[r + ky][p + kx], wv, acc[r][p][co]);
        }
    }
  }
#pragma unroll
  for (int r = 0; r < 2; ++r) {
#pragma unroll
    for (int p = 0; p < 4; ++p) {
      short8 s8;
#pragma unroll
      for (int co = 0; co < 8; ++co) {
        float val = acc[r][p][co] * sc[cg * 8 + co] + sh[cg * 8 + co];
        val = val > 0.f ? val : 0.f;
        acc[r][p][co] = val;
        s8[co] = f2b(val);
      }
      int scg = cg ^ p ^ (xq & 3);
      *(short8*)&fstage[((r * 256 + x0 + p) << 5) + (scg << 3)] = s8;
    }
#pragma unroll
    for (int co = 0; co < 8; ++co) {
      f32x4 o = {acc[r][0][co], acc[r][1][co], acc[r][2][co], acc[r][3][co]};
      f32x4* dst = (f32x4*)&feat[(((size_t)(b * 64 + z * 32 + cg * 8 + co))
                                  << 16) +
                                 ((y0 + r) << 8) + x0];
      __builtin_nontemporal_store(o, dst);
    }
  }
  __syncthreads();
  uchar* fp = z ? featN1 : featN0;
  size_t rowbase = ((size_t)(b * 256 + y0) * 256) * 32;
#pragma unroll
  for (int k = 0; k < 8; ++k) {
    int c = k * 256 + tid;
    int p2 = (c >> 2) & 255;
    int r = c >> 10;
    int cgc = c & 3;
    int scg = cgc ^ (p2 & 3) ^ ((p2 >> 2) & 3);
    short8 v = *(short8*)&fstage[((r * 256 + p2) << 5) + (scg << 3)];
    uint2 pk2;
    pk2.x = pk4q(b2f(v[0]), b2f(v[1]), b2f(v[2]), b2f(v[3]));
    pk2.y = pk4q(b2f(v[4]), b2f(v[5]), b2f(v[6]), b2f(v[7]));
    *(uint2*)(fp + rowbase + (size_t)c * 8) = pk2;
  }
}

// ===== fp8-native MFMA conv3x3: NP fp8 NHWC32 planes in -> fp8 NHWC32 out =====
template <int TX, int NP, int YB, bool POOL>
__global__ __launch_bounds__(256) void k_conv8(
    const uchar* __restrict__ in0, const uchar* __restrict__ in1,
    const uchar* __restrict__ wp, const float* __restrict__ bias,
    const float* __restrict__ g, const float* __restrict__ bb,
    const float* __restrict__ m, const float* __restrict__ vv,
    uchar* __restrict__ out, int H) {
  constexpr int XT = TX + 2;
  constexpr int NR = (TX == 64) ? YB : 2;
  constexpr int YR = ((TX == 64) ? YB : 4) + 2;
  __shared__ u64 tile64[YR * XT * 4];  // 32 B/pos, 8-B chunks
  __shared__ float sc[32], sh[32];
  int tid = threadIdx.x;
  int lane = tid & 63, wid = tid >> 6;
  int W = H;
  int b = blockIdx.z, y0 = blockIdx.y * ((TX == 64) ? YB : 4),
      x0 = blockIdx.x * TX;
  if (tid < 32) {
    float s = g[tid] * rsqrtf(vv[tid] + 1e-5f);
    sc[tid] = s;
    sh[tid] = (bias[tid] - m[tid]) * s + bb[tid];
  }
  int px = lane & 15, g4 = lane >> 4;
  int RB = (TX == 64) ? 0 : (wid >> 1) * 2;
  int wx = (TX == 64) ? wid : (wid & 1);
  f32x4 acc[NR][2];
#pragma unroll
  for (int r = 0; r < NR; ++r)
#pragma unroll
    for (int ct = 0; ct < 2; ++ct) acc[r][ct] = {0.f, 0.f, 0.f, 0.f};

  for (int cb = 0; cb < NP; ++cb) {
    if (cb) __syncthreads();
    const uchar* in = cb ? in1 : in0;
    for (int i = tid; i < YR * XT * 2; i += 256) {
      int ir = i / (XT * 2), rem = i - ir * (XT * 2);
      int xl = rem >> 1, c2 = rem & 1;
      int gy = y0 - 1 + ir, gx = x0 - 1 + xl;
      u64x2 raw = {0, 0};
      if ((unsigned)gy < (unsigned)H && (unsigned)gx < (unsigned)W)
        raw = *(const u64x2*)(in + ((size_t)(b * H + gy) * W + gx) * 32 +
                              c2 * 16);
      int sw = (xl & 3) ^ ((xl >> 2) & 3);
      int base4 = (ir * XT + xl) * 4;
      tile64[base4 + ((c2 * 2) ^ sw)] = raw[0];
      tile64[base4 + ((c2 * 2 + 1) ^ sw)] = raw[1];
    }
    __syncthreads();
    u64 wf[9][2];
#pragma unroll
    for (int tap = 0; tap < 9; ++tap)
#pragma unroll
      for (int ct = 0; ct < 2; ++ct)
        wf[tap][ct] = *(const u64*)(wp + cb * 9216 +
                                    ((((tap * 2 + ct) << 6) + lane) << 3));
#pragma unroll
    for (int dx = 0; dx < 3; ++dx) {
      int xl = wx * 16 + px + dx;
      int cs = g4 ^ (xl & 3) ^ ((xl >> 2) & 3);
      u64 fr[NR + 2];
#pragma unroll
      for (int ir = 0; ir < NR + 2; ++ir)
        fr[ir] = tile64[((RB + ir) * XT + xl) * 4 + cs];
#pragma unroll
      for (int dy = 0; dy < 3; ++dy)
#pragma unroll
        for (int r = 0; r < NR; ++r)
#pragma unroll
          for (int ct = 0; ct < 2; ++ct)
            acc[r][ct] = __builtin_amdgcn_mfma_f32_16x16x32_fp8_fp8(
                (long)wf[dy * 3 + dx][ct], (long)fr[r + dy], acc[r][ct], 0, 0,
                0);
    }
  }
  int xg = x0 + wx * 16 + px;
  if constexpr (POOL) {
    int H2 = H >> 1;
#pragma unroll
    for (int pr = 0; pr < NR / 2; ++pr) {
#pragma unroll
      for (int ct = 0; ct < 2; ++ct) {
        float o4[4];
#pragma unroll
        for (int q = 0; q < 4; ++q) {
          int co = ct * 16 + g4 * 4 + q;
          float v0 = acc[2 * pr][ct][q] * sc[co] + sh[co];
          float v1 = acc[2 * pr + 1][ct][q] * sc[co] + sh[co];
          v0 = v0 > 0.f ? v0 : 0.f;
          v1 = v1 > 0.f ? v1 : 0.f;
          float s2 = v0 + v1;
          o4[q] = 0.25f * (s2 + __shfl_xor(s2, 1, 64));
        }
        if (!(px & 1)) {
          int row = (y0 + RB + 2 * pr) >> 1;
          unsigned pk = pk4q(o4[0], o4[1], o4[2], o4[3]);
          size_t ob = ((size_t)(b * H2 + row) * H2 + (xg >> 1)) * 32 +
                      ct * 16 + g4 * 4;
          *(unsigned*)(out + ob) = pk;
        }
      }
    }
  } else {
#pragma unroll
    for (int r = 0; r < NR; ++r) {
      int y = y0 + RB + r;
#pragma unroll
      for (int ct = 0; ct < 2; ++ct) {
        float o4[4];
#pragma unroll
        for (int q = 0; q < 4; ++q) {
          int co = ct * 16 + g4 * 4 + q;
          float val = acc[r][ct][q] * sc[co] + sh[co];
          o4[q] = val > 0.f ? val : 0.f;
        }
        unsigned pk = pk4q(o4[0], o4[1], o4[2], o4[3]);
        size_t ob = ((size_t)(b * H + y) * W + xg) * 32 + ct * 16 + g4 * 4;
        *(unsigned*)(out + ob) = pk;
      }
    }
  }
}

// ===== bf16 MFMA conv (smallws fallback, LDS weights) =====
template <int TX, int NP, int YB, bool POOL>
__global__ __launch_bounds__(256) void k_conv4(
    const short* __restrict__ in0, const short* __restrict__ in1,
    const float* __restrict__ w, const float* __restrict__ bias,
    const float* __restrict__ g, const float* __restrict__ bb,
    const float* __restrict__ m, const float* __restrict__ vv,
    short* __restrict__ out, int H) {
  constexpr int XT = TX + 2;
  constexpr int NR = (TX == 64) ? YB : 2;
  constexpr int YR = ((TX == 64) ? YB : 4) + 2;
  __shared__ short tile[YR * XT * 32];
  __shared__ short wlds[9216];
  __shared__ float sc[32], sh[32];
  int tid = threadIdx.x;
  int lane = tid & 63, wid = tid >> 6;
  int W = H;
  int b = blockIdx.z, y0 = blockIdx.y * ((TX == 64) ? YB : 4),
      x0 = blockIdx.x * TX;
  if (tid < 32) {
    float s = g[tid] * rsqrtf(vv[tid] + 1e-5f);
    sc[tid] = s;
    sh[tid] = (bias[tid] - m[tid]) * s + bb[tid];
  }
  int px = lane & 15, g4 = lane >> 4;
  int RB = (TX == 64) ? 0 : (wid >> 1) * 2;
  int wx = (TX == 64) ? wid : (wid & 1);
  f32x4 acc[NR][2];
#pragma unroll
  for (int r = 0; r < NR; ++r)
#pragma unroll
    for (int ct = 0; ct < 2; ++ct) acc[r][ct] = {0.f, 0.f, 0.f, 0.f};

  for (int cb = 0; cb < NP; ++cb) {
    if (cb) __syncthreads();
    for (int d = tid; d < 9216; d += 256) {
      int k = d & 7, l = (d >> 3) & 63, ct = (d >> 9) & 1, tap = d >> 10;
      int co = ct * 16 + (l & 15), cin = (l >> 4) * 8 + k;
      wlds[d] = f2b(w[(co * (NP * 32) + cb * 32 + cin) * 9 + tap]);
    }
    const short* in = cb ? in1 : in0;
    for (int i = tid; i < YR * XT * 4; i += 256) {
      int ir = i / (XT * 4), rem = i - ir * (XT * 4);
      int xl = rem >> 2, cg = rem & 3;
      int gy = y0 - 1 + ir, gx = x0 - 1 + xl;
      short8 v = {0, 0, 0, 0, 0, 0, 0, 0};
      if ((unsigned)gy < (unsigned)H && (unsigned)gx < (unsigned)W)
        v = *(const short8*)(in + (((size_t)(b * H + gy) * W + gx) << 5) +
                             cg * 8);
      *(short8*)&tile[(ir * XT + xl) * 32 +
                      ((cg ^ (xl & 3) ^ ((xl >> 2) & 3)) << 3)] = v;
    }
    __syncthreads();
    short8 wf[9][2];
#pragma unroll
    for (int tap = 0; tap < 9; ++tap)
#pragma unroll
      for (int ct = 0; ct < 2; ++ct)
        wf[tap][ct] = *(short8*)&wlds[(((tap * 2 + ct) << 6) + lane) << 3];
#pragma unroll
    for (int dx = 0; dx < 3; ++dx) {
      int xl = wx * 16 + px + dx;
      int cs = (g4 ^ (xl & 3) ^ ((xl >> 2) & 3)) << 3;
      short8 fr[NR + 2];
#pragma unroll
      for (int ir = 0; ir < NR + 2; ++ir)
        fr[ir] = *(short8*)&tile[((RB + ir) * XT + xl) * 32 + cs];
#pragma unroll
      for (int dy = 0; dy < 3; ++dy)
#pragma unroll
        for (int r = 0; r < NR; ++r)
#pragma unroll
          for (int ct = 0; ct < 2; ++ct)
            acc[r][ct] = __builtin_amdgcn_mfma_f32_16x16x32_bf16(
                wf[dy * 3 + dx][ct], fr[r + dy], acc[r][ct], 0, 0, 0);
    }
  }
  int xg = x0 + wx * 16 + px;
  if constexpr (POOL) {
    int H2 = H >> 1;
#pragma unroll
    for (int pr = 0; pr < NR / 2; ++pr) {
#pragma unroll
      for (int ct = 0; ct < 2; ++ct) {
        float o4[4];
#pragma unroll
        for (int q = 0; q < 4; ++q) {
          int co = ct * 16 + g4 * 4 + q;
          float v0 = acc[2 * pr][ct][q] * sc[co] + sh[co];
          float v1 = acc[2 * pr + 1][ct][q] * sc[co] + sh[co];
          v0 = v0 > 0.f ? v0 : 0.f;
          v1 = v1 > 0.f ? v1 : 0.f;
          float s2 = v0 + v1;
          o4[q] = 0.25f * (s2 + __shfl_xor(s2, 1, 64));
        }
        if (!(px & 1)) {
          int row = (y0 + RB + 2 * pr) >> 1;
          uint2 pk;
          pk.x = (unsigned)(unsigned short)f2b(o4[0]) |
                 ((unsigned)(unsigned short)f2b(o4[1]) << 16);
          pk.y = (unsigned)(unsigned short)f2b(o4[2]) |
                 ((unsigned)(unsigned short)f2b(o4[3]) << 16);
          size_t ob = (((size_t)(b * H2 + row) * H2 + (xg >> 1)) << 5) +
                      ct * 16 + g4 * 4;
          *(uint2*)(out + ob) = pk;
        }
      }
    }
  } else {
#pragma unroll
    for (int r = 0; r < NR; ++r) {
      int y = y0 + RB + r;
      size_t ob = (((size_t)(b * H + y) * W + xg) << 5);
#pragma unroll
      for (int ct = 0; ct < 2; ++ct) {
        uint2 pk;
        float o4[4];
#pragma unroll
        for (int q = 0; q < 4; ++q) {
          int co = ct * 16 + g4 * 4 + q;
          float val = acc[r][ct][q] * sc[co] + sh[co];
          o4[q] = val > 0.f ? val : 0.f;
        }
        pk.x = (unsigned)(unsigned short)f2b(o4[0]) |
               ((unsigned)(unsigned short)f2b(o4[1]) << 16);
        pk.y = (unsigned)(unsigned short)f2b(o4[2]) |
               ((unsigned)(unsigned short)f2b(o4[3]) << 16);
        *(uint2*)(out + ob + ct * 16 + g4 * 4) = pk;
      }
    }
  }
}

// ------- smallws front conv (writes fp32 NCHW feat directly) -------
__global__ __launch_bounds__(256) void k_conv_front(
    const float* __restrict__ x, const float* __restrict__ xf,
    const float* __restrict__ w_spa, const float* __restrict__ b_spa,
    const float* __restrict__ w_fre, const float* __restrict__ b_fre,
    const float* __restrict__ g, const float* __restrict__ bb,
    const float* __restrict__ m, const float* __restrict__ vv,
    float* __restrict__ feat) {
  int z = blockIdx.z;
  const float* in = z ? xf : x;
  const float* w = z ? w_fre : w_spa;
  const float* bias = z ? b_fre : b_spa;
  __shared__ float wl[864];
  __shared__ float sc[32], sh[32];
  int tid = threadIdx.x;
  for (int i = tid; i < 864; i += 256) wl[i] = w[i];
  if (tid < 32) {
    int cg = z * 32 + tid;
    float s = g[cg] * rsqrtf(vv[cg] + 1e-5f);
    sc[tid] = s;
    sh[tid] = (bias[tid] - m[cg]) * s + bb[cg];
  }
  __syncthreads();
  int b = blockIdx.y;
  int idx = blockIdx.x * 256 + tid;
  int ry = idx >> 8;
  int xx = idx & 255;
  int y0 = ry * 2;
  const float* inb = in + (size_t)b * 3 * 65536;
  float a0[32], a1[32];
#pragma unroll
  for (int co = 0; co < 32; ++co) {
    a0[co] = 0.f;
    a1[co] = 0.f;
  }
  for (int ci = 0; ci < 3; ++ci) {
    const float* p = inb + (size_t)ci * 65536;
    float v[4][3];
#pragma unroll
    for (int r = 0; r < 4; ++r) {
      int iy = y0 + r - 1;
      bool yok = (unsigned)iy < 256u;
#pragma unroll
      for (int c = 0; c < 3; ++c) {
        int ix = xx + c - 1;
        v[r][c] = (yok && (unsigned)ix < 256u) ? p[iy * 256 + ix] : 0.f;
      }
    }
#pragma unroll
    for (int t9 = 0; t9 < 9; ++t9) {
      int ky = t9 / 3, kx = t9 % 3;
      float v0 = v[ky][kx], v1 = v[ky + 1][kx];
#pragma unroll
      for (int co = 0; co < 32; ++co) {
        float wv = wl[co * 27 + ci * 9 + t9];
        a0[co] = fmaf(v0, wv, a0[co]);
        a1[co] = fmaf(v1, wv, a1[co]);
      }
    }
  }
#pragma unroll
  for (int co = 0; co < 32; ++co) {
    size_t o = ((size_t)(b * 64 + z * 32 + co) * 256 + y0) * 256 + xx;
    float r0 = a0[co] * sc[co] + sh[co];
    float r1 = a1[co] * sc[co] + sh[co];
    feat[o] = r0 > 0.f ? r0 : 0.f;
    feat[o + 256] = r1 > 0.f ? r1 : 0.f;
  }
}

// ---------------- smallws L1: 64ch fp32 NCHW gather ----------
__global__ __launch_bounds__(256) void k_conv1_mfma(
    const float* __restrict__ in, const float* __restrict__ w,
    const float* __restrict__ bias, const float* __restrict__ g,
    const float* __restrict__ bb, const float* __restrict__ m,
    const float* __restrict__ vv, short* __restrict__ out) {
  constexpr int TX = 64, XT = 66;
  __shared__ short tile[4 * XT * 64];
  __shared__ short wlds[9216];
  __shared__ float sc[32], sh[32];
  int tid = threadIdx.x;
  int lane = tid & 63, wid = tid >> 6;
  int b = blockIdx.z, y0 = blockIdx.y * 2, x0 = blockIdx.x * TX;
  if (tid < 32) {
    float s = g[tid] * rsqrtf(vv[tid] + 1e-5f);
    sc[tid] = s;
    sh[tid] = (bias[tid] - m[tid]) * s + bb[tid];
  }
  for (int ir = 0; ir < 4; ++ir) {
    int gy = y0 - 1 + ir;
    bool yok = (unsigned)gy < 256u;
    for (int ch = tid; ch < XT * 8; ch += 256) {
      int xl = ch >> 3, cg = ch & 7;
      int gx = x0 - 1 + xl;
      short8 v = {0, 0, 0, 0, 0, 0, 0, 0};
      if (yok && (unsigned)gx < 256u) {
        const float* p = in + (((size_t)(b * 64 + cg * 8)) << 16) + (gy << 8) + gx;
#pragma unroll
        for (int k = 0; k < 8; ++k) v[k] = f2b(p[(size_t)k << 16]);
      }
      *(short8*)&tile[((ir * XT + xl) << 6) + ((cg ^ (xl & 7)) << 3)] = v;
    }
  }
  int px = lane & 15, g4 = lane >> 4;
  int wx = wid;
  f32x4 acc[2][2];
#pragma unroll
  for (int r = 0; r < 2; ++r)
#pragma unroll
    for (int ct = 0; ct < 2; ++ct) acc[r][ct] = {0.f, 0.f, 0.f, 0.f};
  for (int cb = 0; cb < 2; ++cb) {
    __syncthreads();
    for (int d = tid; d < 9216; d += 256) {
      int k = d & 7, l = (d >> 3) & 63, ct = (d >> 9) & 1, tap = d >> 10;
      int co = ct * 16 + (l & 15), cin = (l >> 4) * 8 + k;
      wlds[d] = f2b(w[(co * 64 + cb * 32 + cin) * 9 + tap]);
    }
    __syncthreads();
    short8 wf[9][2];
#pragma unroll
    for (int tap = 0; tap < 9; ++tap)
#pragma unroll
      for (int ct = 0; ct < 2; ++ct)
        wf[tap][ct] = *(short8*)&wlds[(((tap * 2 + ct) << 6) + lane) << 3];
#pragma unroll
    for (int dx = 0; dx < 3; ++dx) {
      short8 fr[4];
#pragma unroll
      for (int ir = 0; ir < 4; ++ir) {
        int xl = wx * 16 + px + dx;
        fr[ir] = *(short8*)&tile[((ir * XT + xl) << 6) +
                                 (((cb * 4 + g4) ^ (xl & 7)) << 3)];
      }
#pragma unroll
      for (int dy = 0; dy < 3; ++dy)
#pragma unroll
        for (int r = 0; r < 2; ++r)
#pragma unroll
          for (int ct = 0; ct < 2; ++ct)
            acc[r][ct] = __builtin_amdgcn_mfma_f32_16x16x32_bf16(
                wf[dy * 3 + dx][ct], fr[r + dy], acc[r][ct], 0, 0, 0);
    }
  }
#pragma unroll
  for (int r = 0; r < 2; ++r) {
    int y = y0 + r;
    int xg = x0 + wx * 16 + px;
    size_t ob = (((size_t)(b * 256 + y) * 256 + xg) << 5);
#pragma unroll
    for (int ct = 0; ct < 2; ++ct) {
      unsigned short u[4];
#pragma unroll
      for (int q = 0; q < 4; ++q) {
        int co = ct * 16 + g4 * 4 + q;
        float val = acc[r][ct][q] * sc[co] + sh[co];
        val = val > 0.f ? val : 0.f;
        u[q] = (unsigned short)f2b(val);
      }
      uint2 pk;
      pk.x = (unsigned)u[0] | ((unsigned)u[1] << 16);
      pk.y = (unsigned)u[2] | ((unsigned)u[3] << 16);
      *(uint2*)(out + ob + ct * 16 + g4 * 4) = pk;
    }
  }
}

// ===== fused tail: L9 + L10 (@32, in LDS) + global mean + fc, one block/batch ==
template <bool F8>
__global__ __launch_bounds__(256) void k_tail(
    const void* __restrict__ in, const float* __restrict__ w9,
    const float* __restrict__ b9, const float* __restrict__ w10,
    const float* __restrict__ b10, const float* __restrict__ cg9,
    const float* __restrict__ cb9, const float* __restrict__ cm9,
    const float* __restrict__ cv9, const float* __restrict__ cg10,
    const float* __restrict__ cb10, const float* __restrict__ cm10,
    const float* __restrict__ cv10, const float* __restrict__ fw,
    const float* __restrict__ fb, float* __restrict__ logits) {
  __shared__ short tileA[32768];
  __shared__ short tileB[32768];
  __shared__ short wlds[9216];
  __shared__ float sc[2][32], sh[2][32];
  __shared__ float red[16][8];
  __shared__ float smean[32];
  int tid = threadIdx.x;
  int lane = tid & 63, wv = tid >> 6;
  int b = blockIdx.x;
  int px = lane & 15, g4 = lane >> 4;

  if (tid < 64) {
    int l = tid >> 5, c = tid & 31;
    const float* g = l ? cg10 : cg9;
    const float* bb = l ? cb10 : cb9;
    const float* m = l ? cm10 : cm9;
    const float* v = l ? cv10 : cv9;
    const float* bi = l ? b10 : b9;
    float s = g[c] * rsqrtf(v[c] + 1e-5f);
    sc[l][c] = s;
    sh[l][c] = (bi[c] - m[c]) * s + bb[c];
  }
  if constexpr (F8) {
    const uchar* src = (const uchar*)in + (size_t)b * 32768;
    for (int i = tid; i < 2048; i += 256) {
      int p = i >> 1, c2 = i & 1, xc = p & 31;
      uint4v raw = *(const uint4v*)(src + p * 32 + c2 * 16);
      float f[16];
      upk4(raw[0], f + 0);
      upk4(raw[1], f + 4);
      upk4(raw[2], f + 8);
      upk4(raw[3], f + 12);
      short8 o0, o1;
#pragma unroll
      for (int k = 0; k < 8; ++k) {
        o0[k] = f2b(f[k]);
        o1[k] = f2b(f[k + 8]);
      }
      int sw = (xc & 3) ^ ((xc >> 2) & 3);
      *(short8*)&tileA[p * 32 + (((c2 * 2) ^ sw) << 3)] = o0;
      *(short8*)&tileA[p * 32 + (((c2 * 2 + 1) ^ sw) << 3)] = o1;
    }
  } else {
    const short* src = (const short*)in + (size_t)b * 32768;
    for (int i = tid; i < 4096; i += 256) {
      int p = i >> 2, cg = i & 3;
      int xc = p & 31;
      short8 v = *(const short8*)(src + p * 32 + cg * 8);
      *(short8*)&tileA[p * 32 + ((cg ^ (xc & 3) ^ ((xc >> 2) & 3)) << 3)] = v;
    }
  }
  float psum[2][4];
#pragma unroll
  for (int ct = 0; ct < 2; ++ct)
#pragma unroll
    for (int q = 0; q < 4; ++q) psum[ct][q] = 0.f;

  for (int layer = 0; layer < 2; ++layer) {
    if (layer) __syncthreads();
    const float* w = layer ? w10 : w9;
    for (int d = tid; d < 9216; d += 256) {
      int k = d & 7, l = (d >> 3) & 63, ct = (d >> 9) & 1, tap = d >> 10;
      int co = ct * 16 + (l & 15), cin = (l >> 4) * 8 + k;
      wlds[d] = f2b(w[(co * 32 + cin) * 9 + tap]);
    }
    __syncthreads();
    short8 wf[9][2];
#pragma unroll
    for (int tap = 0; tap < 9; ++tap)
#pragma unroll
      for (int ct = 0; ct < 2; ++ct)
        wf[tap][ct] = *(short8*)&wlds[(((tap * 2 + ct) << 6) + lane) << 3];
    const short* ts = layer ? tileB : tileA;
    for (int u = wv; u < 16; u += 4) {
      int rw = u >> 1, cw = u & 1;
      f32x4 acc[4][2];
#pragma unroll
      for (int r = 0; r < 4; ++r)
#pragma unroll
        for (int ct = 0; ct < 2; ++ct) acc[r][ct] = {0.f, 0.f, 0.f, 0.f};
#pragma unroll
      for (int dx = 0; dx < 3; ++dx) {
        int gx = cw * 16 + px + dx - 1;
        bool xok = (unsigned)gx < 32u;
        int cs = (g4 ^ (gx & 3) ^ ((gx >> 2) & 3)) << 3;
        short8 fr[6];
        short8 zz = {0, 0, 0, 0, 0, 0, 0, 0};
#pragma unroll
        for (int ir = 0; ir < 6; ++ir) {
          int gy = rw * 4 + ir - 1;
          fr[ir] = (xok && (unsigned)gy < 32u)
                       ? *(const short8*)&ts[(gy * 32 + gx) * 32 + cs]
                       : zz;
        }
#pragma unroll
        for (int dy = 0; dy < 3; ++dy)
#pragma unroll
          for (int r = 0; r < 4; ++r)
#pragma unroll
            for (int ct = 0; ct < 2; ++ct)
              acc[r][ct] = __builtin_amdgcn_mfma_f32_16x16x32_bf16(
                  wf[dy * 3 + dx][ct], fr[r + dy], acc[r][ct], 0, 0, 0);
      }
      int xc = cw * 16 + px;
#pragma unroll
      for (int r = 0; r < 4; ++r) {
        int y = rw * 4 + r;
#pragma unroll
        for (int ct = 0; ct < 2; ++ct) {
          float v4[4];
#pragma unroll
          for (int q = 0; q < 4; ++q) {
            int co = ct * 16 + g4 * 4 + q;
            float val = acc[r][ct][q] * sc[layer][co] + sh[layer][co];
            v4[q] = val > 0.f ? val : 0.f;
          }
          if (layer == 0) {
            int cg = ct * 2 + (g4 >> 1);
            int scg = cg ^ (xc & 3) ^ ((xc >> 2) & 3);
            uint2 pk;
            pk.x = (unsigned)(unsigned short)f2b(v4[0]) |
                   ((unsigned)(unsigned short)f2b(v4[1]) << 16);
            pk.y = (unsigned)(unsigned short)f2b(v4[2]) |
                   ((unsigned)(unsigned short)f2b(v4[3]) << 16);
            *(uint2*)&tileB[(y * 32 + xc) * 32 + (scg << 3) + (g4 & 1) * 4] = pk;
          } else {
#pragma unroll
            for (int q = 0; q < 4; ++q) psum[ct][q] += v4[q];
          }
        }
      }
    }
  }
#pragma unroll
  for (int o = 1; o < 16; o <<= 1)
#pragma unroll
    for (int ct = 0; ct < 2; ++ct)
#pragma unroll
      for (int q = 0; q < 4; ++q)
        psum[ct][q] += __shfl_xor(psum[ct][q], o, 64);
  if (px == 0) {
#pragma unroll
    for (int ct = 0; ct < 2; ++ct)
#pragma unroll
      for (int q = 0; q < 4; ++q) red[wv * 4 + g4][ct * 4 + q] = psum[ct][q];
  }
  __syncthreads();
  if (tid < 32) {
    int ct = tid >> 4, g4r = (tid >> 2) & 3, q = tid & 3;
    float s = red[g4r][ct * 4 + q] + red[4 + g4r][ct * 4 + q] +
              red[8 + g4r][ct * 4 + q] + red[12 + g4r][ct * 4 + q];
    smean[tid] = s * (1.f / 1024.f);
  }
  __syncthreads();
  if (tid < 2) {
    float s = fb[tid];
    for (int c = 0; c < 32; ++c) s = fmaf(smean[c], fw[tid * 32 + c], s);
    logits[b * 2 + tid] = s;
  }
}

extern "C" void kernel_launch(void* const* d_in, const int* in_sizes, int n_in,
                              void* d_out, int out_size, void* d_ws,
                              size_t ws_size, hipStream_t stream) {
  const float* x = (const float*)d_in[0];
  const float* dmean = (const float*)d_in[1];
  const float* dstd = (const float*)d_in[2];
  const float* w_spa = (const float*)d_in[3];
  const float* b_spa = (const float*)d_in[4];
  const float* w_fre = (const float*)d_in[5];
  const float* b_fre = (const float*)d_in[6];
  const float* bn0_g = (const float*)d_in[7];
  const float* bn0_b = (const float*)d_in[8];
  const float* bn0_m = (const float*)d_in[9];
  const float* bn0_v = (const float*)d_in[10];
  const float* cls_w1 = (const float*)d_in[11];
  const float* cls_b1 = (const float*)d_in[12];
  const float* cls_w = (const float*)d_in[13];
  const float* cls_b = (const float*)d_in[14];
  const float* cbn_g = (const float*)d_in[15];
  const float* cbn_b = (const float*)d_in[16];
  const float* cbn_m = (const float*)d_in[17];
  const float* cbn_v = (const float*)d_in[18];
  const float* fc_w = (const float*)d_in[19];
  const float* fc_b = (const float*)d_in[20];

  float* out = (float*)d_out;
  float* logits = out;     // [16,2] fp32
  float* feat = out + 32;  // [16,64,256,256] fp32 NCHW

  char* ws = (char*)d_ws;
  const size_t MB = 1048576ull;
  bool bigws = ws_size >= 193ull * MB;

  const int WS = 32 * 32 * 9;
  if (bigws) {
    uchar* featN0 = (uchar*)ws;              // 32 MiB fp8 plane z=0
    uchar* featN1 = (uchar*)(ws + 32 * MB);  // 32 MiB fp8 plane z=1
    uchar* bufA = (uchar*)(ws + 64 * MB);    // 32 MiB fp8
    uchar* bufB = (uchar*)ws;                // aliases featN0 (dead after L1)
    uchar* wpack = (uchar*)(ws + 192 * MB);  // 9 sets x 9216 fp8 bytes
    float* D = (float*)(ws + 96 * MB);
    float* M1 = (float*)(ws + 97 * MB);
    float* xf = (float*)(ws + 112 * MB);

    k_init<<<dim3(265), dim3(256), 0, stream>>>(D, cls_w1, cls_w, wpack);
    k_dct1<<<dim3(4, 4, 48), dim3(256), 0, stream>>>(D, x, M1);
    k_dct2<<<dim3(4, 4, 48), dim3(256), 0, stream>>>(M1, D, dmean, dstd, xf);

    k_front_n<<<dim3(128, 16, 2), dim3(256), 0, stream>>>(
        x, xf, w_spa, b_spa, w_fre, b_fre, bn0_g, bn0_b, bn0_m, bn0_v, featN0,
        featN1, feat);
    // L1 (64->32) YB=8, fp8-native MFMA
    k_conv8<64, 2, 8, false><<<dim3(4, 32, 16), dim3(256), 0, stream>>>(
        featN0, featN1, wpack, cls_b1, cbn_g, cbn_b, cbn_m, cbn_v, bufA, 256);
    // L2..L4 @256
    k_conv8<64, 1, 8, false><<<dim3(4, 32, 16), dim3(256), 0, stream>>>(
        bufA, nullptr, wpack + 2 * 9216, cls_b + 0 * 32, cbn_g + 32,
        cbn_b + 32, cbn_m + 32, cbn_v + 32, bufB, 256);
    k_conv8<64, 1, 8, false><<<dim3(4, 32, 16), dim3(256), 0, stream>>>(
        bufB, nullptr, wpack + 3 * 9216, cls_b + 1 * 32, cbn_g + 64,
        cbn_b + 64, cbn_m + 64, cbn_v + 64, bufA, 256);
    k_conv8<64, 1, 8, true><<<dim3(4, 32, 16), dim3(256), 0, stream>>>(
        bufA, nullptr, wpack + 4 * 9216, cls_b + 2 * 32, cbn_g + 96,
        cbn_b + 96, cbn_m + 96, cbn_v + 96, bufB, 256);
    // L5,L6 @128
    k_conv8<64, 1, 8, false><<<dim3(2, 16, 16), dim3(256), 0, stream>>>(
        bufB, nullptr, wpack + 5 * 9216, cls_b + 3 * 32, cbn_g + 128,
        cbn_b + 128, cbn_m + 128, cbn_v + 128, bufA, 128);
    k_conv8<64, 1, 8, true><<<dim3(2, 16, 16), dim3(256), 0, stream>>>(
        bufA, nullptr, wpack + 6 * 9216, cls_b + 4 * 32, cbn_g + 160,
        cbn_b + 160, cbn_m + 160, cbn_v + 160, bufB, 128);
    // L7,L8 @64 (TX=32)
    k_conv8<32, 1, 4, false><<<dim3(2, 16, 16), dim3(256), 0, stream>>>(
        bufB, nullptr, wpack + 7 * 9216, cls_b + 5 * 32, cbn_g + 192,
        cbn_b + 192, cbn_m + 192, cbn_v + 192, bufA, 64);
    k_conv8<32, 1, 4, true><<<dim3(2, 16, 16), dim3(256), 0, stream>>>(
        bufA, nullptr, wpack + 8 * 9216, cls_b + 6 * 32, cbn_g + 224,
        cbn_b + 224, cbn_m + 224, cbn_v + 224, bufB, 64);
    k_tail<true><<<dim3(16), dim3(256), 0, stream>>>(
        bufB, cls_w + 7 * WS, cls_b + 7 * 32, cls_w + 8 * WS, cls_b + 8 * 32,
        cbn_g + 256, cbn_b + 256, cbn_m + 256, cbn_v + 256, cbn_g + 288,
        cbn_b + 288, cbn_m + 288, cbn_v + 288, fc_w, fc_b, logits);
  } else {
    short* bufA = (short*)ws;
    short* bufB = (short*)(ws + 64 * MB);
    float* D = (float*)ws;
    float* M1 = (float*)(ws + 1 * MB);
    float* xf = (float*)(ws + 64 * MB);

    k_build_dct<<<dim3(256), dim3(256), 0, stream>>>(D);
    k_dct1<<<dim3(4, 4, 48), dim3(256), 0, stream>>>(D, x, M1);
    k_dct2<<<dim3(4, 4, 48), dim3(256), 0, stream>>>(M1, D, dmean, dstd, xf);
    k_conv_front<<<dim3(128, 16, 2), dim3(256), 0, stream>>>(
        x, xf, w_spa, b_spa, w_fre, b_fre, bn0_g, bn0_b, bn0_m, bn0_v, feat);
    k_conv1_mfma<<<dim3(4, 128, 16), dim3(256), 0, stream>>>(
        feat, cls_w1, cls_b1, cbn_g, cbn_b, cbn_m, cbn_v, bufA);
    k_conv4<64, 1, 8, false><<<dim3(4, 32, 16), dim3(256), 0, stream>>>(
        bufA, nullptr, cls_w + 0 * WS, cls_b + 0 * 32, cbn_g + 32, cbn_b + 32,
        cbn_m + 32, cbn_v + 32, bufB, 256);
    k_conv4<64, 1, 8, false><<<dim3(4, 32, 16), dim3(256), 0, stream>>>(
        bufB, nullptr, cls_w + 1 * WS, cls_b + 1 * 32, cbn_g + 64, cbn_b + 64,
        cbn_m + 64, cbn_v + 64, bufA, 256);
    k_conv4<64, 1, 8, true><<<dim3(4, 32, 16), dim3(256), 0, stream>>>(
        bufA, nullptr, cls_w + 2 * WS, cls_b + 2 * 32, cbn_g + 96, cbn_b + 96,
        cbn_m + 96, cbn_v + 96, bufB, 256);
    k_conv4<64, 1, 8, false><<<dim3(2, 16, 16), dim3(256), 0, stream>>>(
        bufB, nullptr, cls_w + 3 * WS, cls_b + 3 * 32, cbn_g + 128,
        cbn_b + 128, cbn_m + 128, cbn_v + 128, bufA, 128);
    k_conv4<64, 1, 8, true><<<dim3(2, 16, 16), dim3(256), 0, stream>>>(
        bufA, nullptr, cls_w + 4 * WS, cls_b + 4 * 32, cbn_g + 160,
        cbn_b + 160, cbn_m + 160, cbn_v + 160, bufB, 128);
    k_conv4<32, 1, 4, false><<<dim3(2, 16, 16), dim3(256), 0, stream>>>(
        bufB, nullptr, cls_w + 5 * WS, cls_b + 5 * 32, cbn_g + 192,
        cbn_b + 192, cbn_m + 192, cbn_v + 192, bufA, 64);
    k_conv4<32, 1, 4, true><<<dim3(2, 16, 16), dim3(256), 0, stream>>>(
        bufA, nullptr, cls_w + 6 * WS, cls_b + 6 * 32, cbn_g + 224,
        cbn_b + 224, cbn_m + 224, cbn_v + 224, bufB, 64);
    k_tail<false><<<dim3(16), dim3(256), 0, stream>>>(
        bufB, cls_w + 7 * WS, cls_b + 7 * 32, cls_w + 8 * WS, cls_b + 8 * 32,
        cbn_g + 256, cbn_b + 256, cbn_m + 256, cbn_v + 256, cbn_g + 288,
        cbn_b + 288, cbn_m + 288, cbn_v + 288, fc_w, fc_b, logits);
  }
}